// Round 1
// baseline (5603.825 us; speedup 1.0000x reference)
//
#include <hip/hip_runtime.h>
#include <stdint.h>

constexpr int NN  = 50000;   // nodes
constexpr int NE  = 800000;  // edges
constexpr int NG  = 64;      // graphs
constexpr int H   = 300;     // hidden
constexpr int H2  = 600;     // 2*hidden
constexpr int IND = 20;      // 2*PERIOD
constexpr int NL  = 5;

// ---------------- edge sort (counting sort by dst) ----------------

__global__ void hist_kernel(const int* __restrict__ dst, int* __restrict__ hist) {
  int i = blockIdx.x * blockDim.x + threadIdx.x;
  if (i < NE) atomicAdd(&hist[dst[i]], 1);
}

__global__ __launch_bounds__(1024) void scan_kernel(const int* __restrict__ hist,
                                                    int* __restrict__ offs,
                                                    int* __restrict__ cursor) {
  __shared__ int sdata[1024];
  __shared__ int srun;
  int tid = threadIdx.x;
  if (tid == 0) srun = 0;
  __syncthreads();
  for (int base = 0; base < NN; base += 1024) {
    int i = base + tid;
    int v = (i < NN) ? hist[i] : 0;
    sdata[tid] = v;
    __syncthreads();
    for (int ofs = 1; ofs < 1024; ofs <<= 1) {
      int t = (tid >= ofs) ? sdata[tid - ofs] : 0;
      __syncthreads();
      sdata[tid] += t;
      __syncthreads();
    }
    int run = srun;
    __syncthreads();
    if (i < NN) {
      int excl = run + sdata[tid] - v;
      offs[i] = excl;
      cursor[i] = excl;
    }
    if (tid == 0) srun = run + sdata[1023];
    __syncthreads();
  }
  if (tid == 0) offs[NN] = srun;
}

__global__ void scatter_kernel(const int* __restrict__ src, const int* __restrict__ dst,
                               const float* __restrict__ w, int* __restrict__ cursor,
                               int* __restrict__ ssrc, float* __restrict__ sw) {
  int i = blockIdx.x * blockDim.x + threadIdx.x;
  if (i < NE) {
    int d = dst[i];
    int p = atomicAdd(&cursor[d], 1);
    ssrc[p] = src[i];
    sw[p]   = w[i];
  }
}

// ---------------- input linear: h = x @ linW + linb ----------------

__global__ void lin_kernel(const float* __restrict__ x, const float* __restrict__ W,
                           const float* __restrict__ b, float* __restrict__ h) {
  const long long total = (long long)NN * H;
  long long stride = (long long)gridDim.x * blockDim.x;
  for (long long idx = blockIdx.x * (long long)blockDim.x + threadIdx.x; idx < total;
       idx += stride) {
    int n = (int)(idx / H);
    int f = (int)(idx - (long long)n * H);
    float acc = b[f];
    const float* xr = x + n * IND;
#pragma unroll
    for (int k = 0; k < IND; ++k) acc = fmaf(xr[k], W[k * H + f], acc);
    h[idx] = acc;
  }
}

// ---------------- message aggregation (edges sorted by dst) ----------------

__global__ __launch_bounds__(256) void agg_kernel(const float* __restrict__ h,
                                                  const int* __restrict__ offs,
                                                  const int* __restrict__ ssrc,
                                                  const float* __restrict__ sw,
                                                  float* __restrict__ agg) {
  int n = blockIdx.x;
  int f = threadIdx.x;  // 0..255, covers f and f+256
  int s = offs[n], e = offs[n + 1];
  float a0 = 0.f, a1 = 0.f;
  for (int i = s; i < e; ++i) {
    int sn = ssrc[i];
    float w = sw[i];
    const float* hr = h + (long long)sn * H;
    a0 = fmaf(w, hr[f], a0);
    if (f < H - 256) a1 = fmaf(w, hr[f + 256], a1);
  }
  float* ar = agg + (long long)n * H;
  ar[f] = a0;
  if (f < H - 256) ar[f + 256] = a1;
}

// ---------------- tiled f32 GEMM with optional fused BN+ReLU on A ----------------
// C[M,N] = act(A') @ B + bias ; A' = relu(ascale[k]*A + ashift[k]) if ascale != null

__global__ __launch_bounds__(256) void gemm_kernel(
    const float* __restrict__ A, const float* __restrict__ B,
    const float* __restrict__ bias,
    const float* __restrict__ ascale, const float* __restrict__ ashift,
    float* __restrict__ C, int M, int N, int K) {
  __shared__ float As[16][65];  // [k][m], padded
  __shared__ float Bs[16][64];  // [k][n]
  int tid = threadIdx.x;
  int tx = tid & 15, ty = tid >> 4;
  int bm = blockIdx.x * 64;
  int bn = blockIdx.y * 64;
  float acc[4][4] = {};
  int aRow = tid >> 2;
  int aK = (tid & 3) * 4;
  int bCol = tid & 63;
  int bK0 = (tid >> 6) * 4;
  int kTiles = (K + 15) / 16;
  for (int kt = 0; kt < kTiles; ++kt) {
    int k0 = kt * 16;
#pragma unroll
    for (int j = 0; j < 4; ++j) {
      int gk = k0 + aK + j;
      int gr = bm + aRow;
      float v = 0.f;
      if (gr < M && gk < K) {
        v = A[(long long)gr * K + gk];
        if (ascale) v = fmaxf(fmaf(v, ascale[gk], ashift[gk]), 0.f);
      }
      As[aK + j][aRow] = v;
    }
#pragma unroll
    for (int j = 0; j < 4; ++j) {
      int kk = bK0 + j;
      int gk = k0 + kk;
      int gn = bn + bCol;
      float v = 0.f;
      if (gk < K && gn < N) v = B[(long long)gk * N + gn];
      Bs[kk][bCol] = v;
    }
    __syncthreads();
#pragma unroll
    for (int k = 0; k < 16; ++k) {
      float a[4], b[4];
#pragma unroll
      for (int j = 0; j < 4; ++j) a[j] = As[k][ty * 4 + j];
#pragma unroll
      for (int j = 0; j < 4; ++j) b[j] = Bs[k][tx * 4 + j];
#pragma unroll
      for (int i = 0; i < 4; ++i)
#pragma unroll
        for (int j = 0; j < 4; ++j) acc[i][j] = fmaf(a[i], b[j], acc[i][j]);
    }
    __syncthreads();
  }
#pragma unroll
  for (int i = 0; i < 4; ++i) {
    int r = bm + ty * 4 + i;
    if (r < M) {
#pragma unroll
      for (int j = 0; j < 4; ++j) {
        int cc = bn + tx * 4 + j;
        if (cc < N) C[(long long)r * N + cc] = acc[i][j] + bias[cc];
      }
    }
  }
}

// ---------------- BN column stats / finalize / apply ----------------

__global__ __launch_bounds__(256) void colstats_kernel(const float* __restrict__ P, int M, int C,
                                                       float* __restrict__ sum,
                                                       float* __restrict__ sq) {
  int lane = threadIdx.x & 63;
  int ty = threadIdx.x >> 6;  // 0..3
  int c = blockIdx.x * 64 + lane;
  float s = 0.f, q = 0.f;
  if (c < C) {
    for (int r = blockIdx.y * 4 + ty; r < M; r += gridDim.y * 4) {
      float v = P[(long long)r * C + c];
      s += v;
      q = fmaf(v, v, q);
    }
  }
  __shared__ float ls[4][64], lq[4][64];
  ls[ty][lane] = s;
  lq[ty][lane] = q;
  __syncthreads();
  if (ty == 0 && c < C) {
    s = ls[0][lane] + ls[1][lane] + ls[2][lane] + ls[3][lane];
    q = lq[0][lane] + lq[1][lane] + lq[2][lane] + lq[3][lane];
    atomicAdd(&sum[c], s);
    atomicAdd(&sq[c], q);
  }
}

__global__ void finalize_kernel(const float* __restrict__ sum, const float* __restrict__ sq,
                                const float* __restrict__ g, const float* __restrict__ be,
                                int C, float invM, float* __restrict__ scale,
                                float* __restrict__ shift) {
  int c = blockIdx.x * blockDim.x + threadIdx.x;
  if (c < C) {
    float m = sum[c] * invM;
    float v = sq[c] * invM - m * m;
    float sc = g[c] * rsqrtf(v + 1e-5f);
    scale[c] = sc;
    shift[c] = be[c] - m * sc;
  }
}

__global__ void bn_apply_kernel(const float* __restrict__ t, const float* __restrict__ scale,
                                const float* __restrict__ shift, int C, long long total,
                                int do_relu, float* __restrict__ out) {
  long long stride = (long long)gridDim.x * blockDim.x;
  for (long long idx = blockIdx.x * (long long)blockDim.x + threadIdx.x; idx < total;
       idx += stride) {
    int c = (int)(idx % C);
    float v = fmaf(t[idx], scale[c], shift[c]);
    if (do_relu) v = fmaxf(v, 0.f);
    out[idx] = v;
  }
}

// ---------------- graph pooling ----------------

__global__ void bounds_kernel(const int* __restrict__ batch, int* __restrict__ gstart) {
  int g = threadIdx.x;
  if (g > NG) return;
  if (g == NG) { gstart[NG] = NN; return; }
  int lo = 0, hi = NN;
  while (lo < hi) {
    int mid = (lo + hi) >> 1;
    if (batch[mid] < g) lo = mid + 1; else hi = mid;
  }
  gstart[g] = lo;
}

__global__ __launch_bounds__(320) void pool_kernel(const float* __restrict__ h,
                                                   const int* __restrict__ gstart,
                                                   float* __restrict__ xpool) {
  int g = blockIdx.x;
  int f = threadIdx.x;
  if (f >= H) return;
  int s = gstart[g], e = gstart[g + 1];
  float acc = 0.f;
  for (int r = s + blockIdx.y; r < e; r += gridDim.y) acc += h[(long long)r * H + f];
  atomicAdd(&xpool[g * H + f], acc);
}

// ---------------- driver ----------------

extern "C" void kernel_launch(void* const* d_in, const int* in_sizes, int n_in,
                              void* d_out, int out_size, void* d_ws, size_t ws_size,
                              hipStream_t stream) {
  const int*   batch = (const int*)d_in[0];
  const float* x     = (const float*)d_in[1];
  const int*   eidx  = (const int*)d_in[2];
  const float* eattr = (const float*)d_in[3];
  const float* linW  = (const float*)d_in[4];
  const float* linb  = (const float*)d_in[5];
  const float* W1s   = (const float*)d_in[6];
  const float* b1s   = (const float*)d_in[7];
  const float* g1s   = (const float*)d_in[8];
  const float* be1s  = (const float*)d_in[9];
  const float* W2s   = (const float*)d_in[10];
  const float* b2s   = (const float*)d_in[11];
  const float* gos   = (const float*)d_in[12];
  const float* bos   = (const float*)d_in[13];

  const int* esrc = eidx;
  const int* edst = eidx + NE;

  float* hbuf   = (float*)d_ws;                  // NN*H
  float* aggbuf = hbuf + (long long)NN * H;      // NN*H
  float* tbuf   = aggbuf + (long long)NN * H;    // NN*H2
  int*   hist   = (int*)(tbuf + (long long)NN * H2);  // NN
  int*   offs   = hist + NN;                     // NN+1 (padded to NN+64)
  int*   cursor = offs + (NN + 64);              // NN
  int*   ssrc   = cursor + NN;                   // NE
  float* sw     = (float*)(ssrc + NE);           // NE
  float* stats  = sw + NE;
  float* sum1   = stats;            // H2
  float* sq1    = sum1 + H2;        // H2
  float* sum2   = sq1 + H2;         // H
  float* sq2    = sum2 + H;         // H
  float* scale1 = sq2 + H;          // H2
  float* shift1 = scale1 + H2;      // H2
  float* scale2 = shift1 + H2;      // H
  float* shift2 = scale2 + H;       // H
  int*   gstart = (int*)(shift2 + H);  // NG+1
  size_t needed = (size_t)((char*)(gstart + NG + 1) - (char*)d_ws);
  if (ws_size < needed) return;  // workspace too small: fail loudly (zeros out)

  float* hout  = (float*)d_out;
  float* xpool = hout + (long long)NN * H;

  // edge sort
  hipMemsetAsync(hist, 0, NN * sizeof(int), stream);
  hist_kernel<<<(NE + 255) / 256, 256, 0, stream>>>(edst, hist);
  scan_kernel<<<1, 1024, 0, stream>>>(hist, offs, cursor);
  scatter_kernel<<<(NE + 255) / 256, 256, 0, stream>>>(esrc, edst, eattr, cursor, ssrc, sw);

  // h = x @ linW + linb
  lin_kernel<<<2048, 256, 0, stream>>>(x, linW, linb, hbuf);

  for (int i = 0; i < NL; ++i) {
    agg_kernel<<<NN, 256, 0, stream>>>(hbuf, offs, ssrc, sw, aggbuf);
    hipMemsetAsync(stats, 0, (H2 * 2 + H * 2) * sizeof(float), stream);

    dim3 g1((NN + 63) / 64, (H2 + 63) / 64);
    gemm_kernel<<<g1, 256, 0, stream>>>(aggbuf, W1s + (long long)i * H * H2,
                                        b1s + i * H2, nullptr, nullptr,
                                        tbuf, NN, H2, H);
    colstats_kernel<<<dim3((H2 + 63) / 64, 128), 256, 0, stream>>>(tbuf, NN, H2, sum1, sq1);
    finalize_kernel<<<(H2 + 255) / 256, 256, 0, stream>>>(sum1, sq1, g1s + i * H2,
                                                          be1s + i * H2, H2, 1.f / NN,
                                                          scale1, shift1);
    dim3 g2((NN + 63) / 64, (H + 63) / 64);
    gemm_kernel<<<g2, 256, 0, stream>>>(tbuf, W2s + (long long)i * H2 * H,
                                        b2s + i * H, scale1, shift1,
                                        hbuf, NN, H, H2);
    colstats_kernel<<<dim3((H + 63) / 64, 128), 256, 0, stream>>>(hbuf, NN, H, sum2, sq2);
    finalize_kernel<<<1, 512, 0, stream>>>(sum2, sq2, gos + i * H, bos + i * H, H,
                                           1.f / NN, scale2, shift2);
    float* dst = (i == NL - 1) ? hout : hbuf;
    bn_apply_kernel<<<2048, 256, 0, stream>>>(hbuf, scale2, shift2, H,
                                              (long long)NN * H, (i < NL - 1) ? 1 : 0, dst);
  }

  // pooling
  hipMemsetAsync(xpool, 0, NG * H * sizeof(float), stream);
  bounds_kernel<<<1, 128, 0, stream>>>(batch, gstart);
  pool_kernel<<<dim3(NG, 8), 320, 0, stream>>>(hout, gstart, xpool);
}

// Round 3
// 3697.916 us; speedup vs baseline: 1.5154x; 1.5154x over previous
//
#include <hip/hip_runtime.h>
#include <stdint.h>

typedef __bf16 bf16x8 __attribute__((ext_vector_type(8)));
typedef float f32x4 __attribute__((ext_vector_type(4)));

constexpr int NN  = 50000;   // nodes
constexpr int NE  = 800000;  // edges
constexpr int NG  = 64;      // graphs
constexpr int H   = 300;     // hidden
constexpr int H2  = 600;     // 2*hidden
constexpr int IND = 20;      // 2*PERIOD
constexpr int NL  = 5;

constexpr int MP  = 50048;   // rows padded to multiple of 128
constexpr int KP1 = 320;     // padded K stride for agg/u buffers (mult of 32)
constexpr int KP2 = 608;     // padded K stride for t buffers (mult of 32)
constexpr int NP1 = 640;     // padded N for gemm1 (5 x 128)
constexpr int NP2 = 384;     // padded N for gemm2 (3 x 128)

// ---------------- bf16 helpers (RNE) + split-precision ----------------
static __device__ __forceinline__ ushort f2bf(float f) {
  uint32_t u = __float_as_uint(f);
  return (ushort)((u + 0x7FFFu + ((u >> 16) & 1u)) >> 16);
}
static __device__ __forceinline__ float bf1(ushort s) { return __uint_as_float((uint32_t)s << 16); }
static __device__ __forceinline__ float bflo(uint32_t u) { return __uint_as_float(u << 16); }
static __device__ __forceinline__ float bfhi(uint32_t u) { return __uint_as_float(u & 0xFFFF0000u); }
// split v into hi/lo bf16 pair (hi + lo ~= v with ~2^-17 rel err)
static __device__ __forceinline__ void split2(float v, ushort& hi, ushort& lo) {
  hi = f2bf(v);
  lo = f2bf(v - bf1(hi));
}

// ---------------- edge sort (counting sort by dst) ----------------

__global__ void hist_kernel(const int* __restrict__ dst, int* __restrict__ hist) {
  int i = blockIdx.x * blockDim.x + threadIdx.x;
  if (i < NE) atomicAdd(&hist[dst[i]], 1);
}

__global__ __launch_bounds__(1024) void scan_kernel(const int* __restrict__ hist,
                                                    int* __restrict__ offs,
                                                    int* __restrict__ cursor) {
  __shared__ int sdata[1024];
  __shared__ int srun;
  int tid = threadIdx.x;
  if (tid == 0) srun = 0;
  __syncthreads();
  for (int base = 0; base < NN; base += 1024) {
    int i = base + tid;
    int v = (i < NN) ? hist[i] : 0;
    sdata[tid] = v;
    __syncthreads();
    for (int ofs = 1; ofs < 1024; ofs <<= 1) {
      int t = (tid >= ofs) ? sdata[tid - ofs] : 0;
      __syncthreads();
      sdata[tid] += t;
      __syncthreads();
    }
    int run = srun;
    __syncthreads();
    if (i < NN) {
      int excl = run + sdata[tid] - v;
      offs[i] = excl;
      cursor[i] = excl;
    }
    if (tid == 0) srun = run + sdata[1023];
    __syncthreads();
  }
  if (tid == 0) offs[NN] = srun;
}

__global__ void scatter_kernel(const int* __restrict__ src, const int* __restrict__ dst,
                               const float* __restrict__ w, int* __restrict__ cursor,
                               int* __restrict__ ssrc, float* __restrict__ sw) {
  int i = blockIdx.x * blockDim.x + threadIdx.x;
  if (i < NE) {
    int d = dst[i];
    int p = atomicAdd(&cursor[d], 1);
    ssrc[p] = src[i];
    sw[p]   = w[i];
  }
}

// ---------------- pad zeroing for pair buffers ----------------
// zero rows [NN,MP) fully and cols [Ntrue,KPAD) for rows [0,NN)

__global__ void padzero_kernel(ushort* __restrict__ bh, ushort* __restrict__ bl,
                               int KPAD, int Ntrue) {
  long long nA = (long long)(MP - NN) * KPAD;
  int padc = KPAD - Ntrue;
  long long nB = (long long)NN * padc;
  long long total = nA + nB;
  long long stride = (long long)gridDim.x * blockDim.x;
  for (long long i = blockIdx.x * (long long)blockDim.x + threadIdx.x; i < total; i += stride) {
    long long off;
    if (i < nA) {
      off = (long long)NN * KPAD + i;
    } else {
      long long j = i - nA;
      long long r = j / padc;
      long long c = Ntrue + (j - r * padc);
      off = r * KPAD + c;
    }
    bh[off] = 0;
    bl[off] = 0;
  }
}

// ---------------- weight pre-pack into hi/lo pairs: Bp[n][k] = W[k][n] ----------------

__global__ void packW1_kernel(const float* __restrict__ W1s, ushort* __restrict__ Wh,
                              ushort* __restrict__ Wl) {
  int idx = blockIdx.x * blockDim.x + threadIdx.x;
  if (idx >= NL * NP1 * KP1) return;
  int i = idx / (NP1 * KP1);
  int rem = idx - i * (NP1 * KP1);
  int n = rem / KP1;
  int k = rem - n * KP1;
  float v = (n < H2 && k < H) ? W1s[((long long)i * H + k) * H2 + n] : 0.f;
  ushort hi, lo;
  split2(v, hi, lo);
  Wh[idx] = hi;
  Wl[idx] = lo;
}

__global__ void packW2_kernel(const float* __restrict__ W2s, ushort* __restrict__ Wh,
                              ushort* __restrict__ Wl) {
  int idx = blockIdx.x * blockDim.x + threadIdx.x;
  if (idx >= NL * NP2 * KP2) return;
  int i = idx / (NP2 * KP2);
  int rem = idx - i * (NP2 * KP2);
  int n = rem / KP2;
  int k = rem - n * KP2;
  float v = (n < H && k < H2) ? W2s[((long long)i * H2 + k) * H + n] : 0.f;
  ushort hi, lo;
  split2(v, hi, lo);
  Wh[idx] = hi;
  Wl[idx] = lo;
}

// ---------------- input linear: h = x @ linW + linb (f32 out, stride H) ----------------

__global__ void lin_kernel(const float* __restrict__ x, const float* __restrict__ W,
                           const float* __restrict__ b, float* __restrict__ h) {
  int idx = blockIdx.x * blockDim.x + threadIdx.x;
  if (idx >= NN * H) return;
  int n = idx / H;
  int f = idx - n * H;
  float acc = b[f];
  const float* xr = x + n * IND;
#pragma unroll
  for (int k = 0; k < IND; ++k) acc = fmaf(xr[k], W[k * H + f], acc);
  h[idx] = acc;
}

// ---------------- aggregation: f32 h in, bf16-pair agg out ----------------

__global__ __launch_bounds__(192) void agg_kernel(const float* __restrict__ h,
                                                  const int* __restrict__ offs,
                                                  const int* __restrict__ ssrc,
                                                  const float* __restrict__ sw,
                                                  ushort* __restrict__ aggh,
                                                  ushort* __restrict__ aggl) {
  int n = blockIdx.x;
  int t = threadIdx.x;
  if (t >= H / 2) return;
  int s = offs[n], e = offs[n + 1];
  float a0 = 0.f, a1 = 0.f;
  for (int i = s; i < e; ++i) {
    int sn = ssrc[i];
    float w = sw[i];
    float2 hv = *reinterpret_cast<const float2*>(h + (long long)sn * H + 2 * t);
    a0 = fmaf(w, hv.x, a0);
    a1 = fmaf(w, hv.y, a1);
  }
  ushort h0, l0, h1, l1;
  split2(a0, h0, l0);
  split2(a1, h1, l1);
  long long base = (long long)n * KP1 + 2 * t;
  *reinterpret_cast<uint32_t*>(aggh + base) = (uint32_t)h0 | ((uint32_t)h1 << 16);
  *reinterpret_cast<uint32_t*>(aggl + base) = (uint32_t)l0 | ((uint32_t)l1 << 16);
}

// ---------------- split-precision bf16 MFMA GEMM ----------------
// C = (Ah+Al) @ (Bh+Bl)^T_packed + bias, 3-term: ah*bh + al*bh + ah*bl
// A: [MP][KPAD] pairs. Bp: [Npad][KPAD] pairs (Bp[n][k] = B[k][n]).
// C written as bf16 pairs at stride Cstride, rows < M, cols < Ntrue.

__global__ __launch_bounds__(256) void gemm_mfma(
    const ushort* __restrict__ Ah, const ushort* __restrict__ Al,
    const ushort* __restrict__ Bh, const ushort* __restrict__ Bl,
    const float* __restrict__ bias, ushort* __restrict__ Ch, ushort* __restrict__ Cl,
    int M, int Ntrue, int Ktiles, int KPAD, int Cstride) {
  int tid = threadIdx.x;
  int lane = tid & 63, wid = tid >> 6;
  int wm = wid >> 1, wn = wid & 1;
  int lm = lane & 15, lg = lane >> 4;
  long long bm = (long long)blockIdx.x * 128;
  long long bn = (long long)blockIdx.y * 128;

  long long aoff = (bm + wm * 64 + lm) * KPAD + lg * 8;
  long long boff = (bn + wn * 64 + lm) * KPAD + lg * 8;
  const ushort* Abh = Ah + aoff;
  const ushort* Abl = Al + aoff;
  const ushort* Bbh = Bh + boff;
  const ushort* Bbl = Bl + boff;

  f32x4 acc[4][4] = {};

  for (int kt = 0; kt < Ktiles; ++kt) {
    int ko = kt * 32;
    bf16x8 ah[4], al[4], bh[4], bl[4];
#pragma unroll
    for (int i = 0; i < 4; ++i) {
      long long o = (long long)i * 16 * KPAD + ko;
      ah[i] = *reinterpret_cast<const bf16x8*>(Abh + o);
      al[i] = *reinterpret_cast<const bf16x8*>(Abl + o);
      bh[i] = *reinterpret_cast<const bf16x8*>(Bbh + o);
      bl[i] = *reinterpret_cast<const bf16x8*>(Bbl + o);
    }
#pragma unroll
    for (int mf = 0; mf < 4; ++mf)
#pragma unroll
      for (int nf = 0; nf < 4; ++nf) {
        acc[mf][nf] = __builtin_amdgcn_mfma_f32_16x16x32_bf16(ah[mf], bl[nf], acc[mf][nf], 0, 0, 0);
        acc[mf][nf] = __builtin_amdgcn_mfma_f32_16x16x32_bf16(al[mf], bh[nf], acc[mf][nf], 0, 0, 0);
        acc[mf][nf] = __builtin_amdgcn_mfma_f32_16x16x32_bf16(ah[mf], bh[nf], acc[mf][nf], 0, 0, 0);
      }
  }

  int colb = (int)bn + wn * 64 + lm;
#pragma unroll
  for (int nf = 0; nf < 4; ++nf) {
    int col = colb + nf * 16;
    if (col < Ntrue) {
      float bv = bias[col];
#pragma unroll
      for (int mf = 0; mf < 4; ++mf) {
        int row = (int)bm + wm * 64 + mf * 16 + lg * 4;
        f32x4 v = acc[mf][nf];
#pragma unroll
        for (int e = 0; e < 4; ++e) {
          if (row + e < M) {
            float w = v[e] + bv;
            ushort hi, lo;
            split2(w, hi, lo);
            long long o = (long long)(row + e) * Cstride + col;
            Ch[o] = hi;
            Cl[o] = lo;
          }
        }
      }
    }
  }
}

// ---------------- BN column stats (pair input) / finalize ----------------

__global__ __launch_bounds__(256) void colstats_kernel(const ushort* __restrict__ Ph,
                                                       const ushort* __restrict__ Pl, int M,
                                                       int C, int stride,
                                                       float* __restrict__ sum,
                                                       float* __restrict__ sq) {
  int lane = threadIdx.x & 63;
  int ty = threadIdx.x >> 6;  // 0..3
  int c = blockIdx.x * 64 + lane;
  float s = 0.f, q = 0.f;
  if (c < C) {
    for (int r = blockIdx.y * 4 + ty; r < M; r += gridDim.y * 4) {
      long long o = (long long)r * stride + c;
      float v = bf1(Ph[o]) + bf1(Pl[o]);
      s += v;
      q = fmaf(v, v, q);
    }
  }
  __shared__ float ls[4][64], lq[4][64];
  ls[ty][lane] = s;
  lq[ty][lane] = q;
  __syncthreads();
  if (ty == 0 && c < C) {
    s = ls[0][lane] + ls[1][lane] + ls[2][lane] + ls[3][lane];
    q = lq[0][lane] + lq[1][lane] + lq[2][lane] + lq[3][lane];
    atomicAdd(&sum[c], s);
    atomicAdd(&sq[c], q);
  }
}

__global__ void finalize_kernel(const float* __restrict__ sum, const float* __restrict__ sq,
                                const float* __restrict__ g, const float* __restrict__ be,
                                int C, float invM, float* __restrict__ scale,
                                float* __restrict__ shift) {
  int c = blockIdx.x * blockDim.x + threadIdx.x;
  if (c < C) {
    float m = sum[c] * invM;
    float v = sq[c] * invM - m * m;
    float sc = g[c] * rsqrtf(v + 1e-5f);
    scale[c] = sc;
    shift[c] = be[c] - m * sc;
  }
}

// ---------------- BN apply ----------------
// bn1: in-place on t pairs (stride KP2), relu, re-split
__global__ void bn1_kernel(ushort* __restrict__ th_, ushort* __restrict__ tl_,
                           const float* __restrict__ scale, const float* __restrict__ shift) {
  int idx = blockIdx.x * blockDim.x + threadIdx.x;
  if (idx >= NN * (H2 / 2)) return;
  int r = idx / (H2 / 2);
  int p = idx - r * (H2 / 2);
  int c = 2 * p;
  long long base = (long long)r * KP2 + c;
  uint32_t uh = *reinterpret_cast<uint32_t*>(th_ + base);
  uint32_t ul = *reinterpret_cast<uint32_t*>(tl_ + base);
  float v0 = bflo(uh) + bflo(ul);
  float v1 = bfhi(uh) + bfhi(ul);
  float w0 = fmaxf(fmaf(v0, scale[c], shift[c]), 0.f);
  float w1 = fmaxf(fmaf(v1, scale[c + 1], shift[c + 1]), 0.f);
  ushort h0, l0, h1, l1;
  split2(w0, h0, l0);
  split2(w1, h1, l1);
  *reinterpret_cast<uint32_t*>(th_ + base) = (uint32_t)h0 | ((uint32_t)h1 << 16);
  *reinterpret_cast<uint32_t*>(tl_ + base) = (uint32_t)l0 | ((uint32_t)l1 << 16);
}

// bn2: pairs (stride KP1) -> f32 h (stride H); relu unless LAST
template <bool LAST>
__global__ void bn2_kernel(const ushort* __restrict__ uh_, const ushort* __restrict__ ul_,
                           const float* __restrict__ scale, const float* __restrict__ shift,
                           float* __restrict__ out) {
  int idx = blockIdx.x * blockDim.x + threadIdx.x;
  if (idx >= NN * (H / 2)) return;
  int r = idx / (H / 2);
  int p = idx - r * (H / 2);
  int c = 2 * p;
  long long base = (long long)r * KP1 + c;
  uint32_t uh = *reinterpret_cast<const uint32_t*>(uh_ + base);
  uint32_t ul = *reinterpret_cast<const uint32_t*>(ul_ + base);
  float v0 = bflo(uh) + bflo(ul);
  float v1 = bfhi(uh) + bfhi(ul);
  float w0 = fmaf(v0, scale[c], shift[c]);
  float w1 = fmaf(v1, scale[c + 1], shift[c + 1]);
  if (!LAST) {
    w0 = fmaxf(w0, 0.f);
    w1 = fmaxf(w1, 0.f);
  }
  float2 wv = make_float2(w0, w1);
  *reinterpret_cast<float2*>(out + (long long)r * H + c) = wv;
}

// ---------------- graph pooling ----------------

__global__ void bounds_kernel(const int* __restrict__ batch, int* __restrict__ gstart) {
  int g = threadIdx.x;
  if (g > NG) return;
  if (g == NG) { gstart[NG] = NN; return; }
  int lo = 0, hi = NN;
  while (lo < hi) {
    int mid = (lo + hi) >> 1;
    if (batch[mid] < g) lo = mid + 1; else hi = mid;
  }
  gstart[g] = lo;
}

__global__ __launch_bounds__(320) void pool_kernel(const float* __restrict__ h,
                                                   const int* __restrict__ gstart,
                                                   float* __restrict__ xpool) {
  int g = blockIdx.x;
  int f = threadIdx.x;
  if (f >= H) return;
  int s = gstart[g], e = gstart[g + 1];
  float acc = 0.f;
  for (int r = s + blockIdx.y; r < e; r += gridDim.y) acc += h[(long long)r * H + f];
  atomicAdd(&xpool[g * H + f], acc);
}

// ---------------- driver ----------------

extern "C" void kernel_launch(void* const* d_in, const int* in_sizes, int n_in,
                              void* d_out, int out_size, void* d_ws, size_t ws_size,
                              hipStream_t stream) {
  const int*   batch = (const int*)d_in[0];
  const float* x     = (const float*)d_in[1];
  const int*   eidx  = (const int*)d_in[2];
  const float* eattr = (const float*)d_in[3];
  const float* linW  = (const float*)d_in[4];
  const float* linb  = (const float*)d_in[5];
  const float* W1s   = (const float*)d_in[6];
  const float* b1s   = (const float*)d_in[7];
  const float* g1s   = (const float*)d_in[8];
  const float* be1s  = (const float*)d_in[9];
  const float* W2s   = (const float*)d_in[10];
  const float* b2s   = (const float*)d_in[11];
  const float* gos   = (const float*)d_in[12];
  const float* bos   = (const float*)d_in[13];

  const int* esrc = eidx;
  const int* edst = eidx + NE;

  char* p = (char*)d_ws;
  auto alloc = [&](size_t bytes) {
    char* r = p;
    p += (bytes + 255) & ~(size_t)255;
    return r;
  };
  ushort* th   = (ushort*)alloc((size_t)MP * KP2 * 2);   // t pairs (then t' pairs)
  ushort* tl   = (ushort*)alloc((size_t)MP * KP2 * 2);
  ushort* aggh = (ushort*)alloc((size_t)MP * KP1 * 2);   // agg pairs; reused as u pairs
  ushort* aggl = (ushort*)alloc((size_t)MP * KP1 * 2);
  ushort* W1h  = (ushort*)alloc((size_t)NL * NP1 * KP1 * 2);
  ushort* W1l  = (ushort*)alloc((size_t)NL * NP1 * KP1 * 2);
  ushort* W2h  = (ushort*)alloc((size_t)NL * NP2 * KP2 * 2);
  ushort* W2l  = (ushort*)alloc((size_t)NL * NP2 * KP2 * 2);
  int*    hist   = (int*)alloc((size_t)NN * 4);
  int*    offs   = (int*)alloc((size_t)(NN + 64) * 4);
  int*    cursor = (int*)alloc((size_t)NN * 4);
  int*    ssrc   = (int*)alloc((size_t)NE * 4);
  float*  sw     = (float*)alloc((size_t)NE * 4);
  float*  sum1   = (float*)alloc((size_t)(H2 * 2 + H * 2) * 4);
  float*  sq1    = sum1 + H2;
  float*  sum2   = sq1 + H2;
  float*  sq2    = sum2 + H;
  float*  scale1 = (float*)alloc((size_t)(H2 * 2 + H * 2) * 4);
  float*  shift1 = scale1 + H2;
  float*  scale2 = shift1 + H2;
  float*  shift2 = scale2 + H;
  int*    gstart = (int*)alloc((size_t)(NG + 1) * 4);
  size_t needed = (size_t)(p - (char*)d_ws);
  if (ws_size < needed) return;

  float* hout  = (float*)d_out;               // also the inter-layer f32 h buffer
  float* xpool = hout + (long long)NN * H;

  // zero the MFMA pad regions of the pair buffers
  padzero_kernel<<<1024, 256, 0, stream>>>(th, tl, KP2, H2);
  padzero_kernel<<<1024, 256, 0, stream>>>(aggh, aggl, KP1, H);

  // weight pre-pack (hi/lo)
  packW1_kernel<<<(NL * NP1 * KP1 + 255) / 256, 256, 0, stream>>>(W1s, W1h, W1l);
  packW2_kernel<<<(NL * NP2 * KP2 + 255) / 256, 256, 0, stream>>>(W2s, W2h, W2l);

  // edge sort
  hipMemsetAsync(hist, 0, (size_t)NN * 4, stream);
  hist_kernel<<<(NE + 255) / 256, 256, 0, stream>>>(edst, hist);
  scan_kernel<<<1, 1024, 0, stream>>>(hist, offs, cursor);
  scatter_kernel<<<(NE + 255) / 256, 256, 0, stream>>>(esrc, edst, eattr, cursor, ssrc, sw);

  // h0 = x @ linW + linb (f32, into hout)
  lin_kernel<<<(NN * H + 255) / 256, 256, 0, stream>>>(x, linW, linb, hout);

  for (int i = 0; i < NL; ++i) {
    agg_kernel<<<NN, 192, 0, stream>>>(hout, offs, ssrc, sw, aggh, aggl);
    hipMemsetAsync(sum1, 0, (size_t)(H2 * 2 + H * 2) * 4, stream);

    // t = agg @ W1 + b1  (pairs out)
    gemm_mfma<<<dim3(MP / 128, NP1 / 128), 256, 0, stream>>>(
        aggh, aggl, W1h + (size_t)i * NP1 * KP1, W1l + (size_t)i * NP1 * KP1,
        b1s + (size_t)i * H2, th, tl, NN, H2, KP1 / 32, KP1, KP2);
    colstats_kernel<<<dim3((H2 + 63) / 64, 128), 256, 0, stream>>>(th, tl, NN, H2, KP2, sum1, sq1);
    finalize_kernel<<<(H2 + 255) / 256, 256, 0, stream>>>(sum1, sq1, g1s + (size_t)i * H2,
                                                          be1s + (size_t)i * H2, H2, 1.f / NN,
                                                          scale1, shift1);
    bn1_kernel<<<(NN * (H2 / 2) + 255) / 256, 256, 0, stream>>>(th, tl, scale1, shift1);

    // u = t' @ W2 + b2 (pairs into aggh/aggl, stride KP1)
    gemm_mfma<<<dim3(MP / 128, NP2 / 128), 256, 0, stream>>>(
        th, tl, W2h + (size_t)i * NP2 * KP2, W2l + (size_t)i * NP2 * KP2,
        b2s + (size_t)i * H, aggh, aggl, NN, H, KP2 / 32, KP2, KP1);
    colstats_kernel<<<dim3((H + 63) / 64, 128), 256, 0, stream>>>(aggh, aggl, NN, H, KP1, sum2, sq2);
    finalize_kernel<<<1, 512, 0, stream>>>(sum2, sq2, gos + (size_t)i * H, bos + (size_t)i * H, H,
                                           1.f / NN, scale2, shift2);
    if (i < NL - 1) {
      bn2_kernel<false><<<(NN * (H / 2) + 255) / 256, 256, 0, stream>>>(aggh, aggl, scale2,
                                                                        shift2, hout);
    } else {
      bn2_kernel<true><<<(NN * (H / 2) + 255) / 256, 256, 0, stream>>>(aggh, aggl, scale2,
                                                                       shift2, hout);
    }
  }

  // pooling
  hipMemsetAsync(xpool, 0, (size_t)NG * H * 4, stream);
  bounds_kernel<<<1, 128, 0, stream>>>(batch, gstart);
  pool_kernel<<<dim3(NG, 8), 320, 0, stream>>>(hout, gstart, xpool);
}

// Round 4
// 3294.329 us; speedup vs baseline: 1.7011x; 1.1225x over previous
//
#include <hip/hip_runtime.h>
#include <stdint.h>

typedef __bf16 bf16x8 __attribute__((ext_vector_type(8)));
typedef float f32x4 __attribute__((ext_vector_type(4)));

constexpr int NN  = 50000;   // nodes
constexpr int NE  = 800000;  // edges
constexpr int NG  = 64;      // graphs
constexpr int H   = 300;     // hidden
constexpr int H2  = 600;     // 2*hidden
constexpr int IND = 20;      // 2*PERIOD
constexpr int NL  = 5;

constexpr int MP  = 50048;   // rows padded to multiple of 128
constexpr int KP1 = 320;     // padded K stride for agg/u buffers (mult of 32)
constexpr int KP2 = 608;     // padded K stride for t buffers (mult of 32)
constexpr int NP1 = 640;     // padded N for gemm1 (5 x 128)
constexpr int NP2 = 384;     // padded N for gemm2 (3 x 128)

// ---------------- bf16 helpers (RNE) + split-precision ----------------
static __device__ __forceinline__ ushort f2bf(float f) {
  uint32_t u = __float_as_uint(f);
  return (ushort)((u + 0x7FFFu + ((u >> 16) & 1u)) >> 16);
}
static __device__ __forceinline__ float bf1(ushort s) { return __uint_as_float((uint32_t)s << 16); }
static __device__ __forceinline__ float bflo(uint32_t u) { return __uint_as_float(u << 16); }
static __device__ __forceinline__ float bfhi(uint32_t u) { return __uint_as_float(u & 0xFFFF0000u); }
// split v into hi/lo bf16 pair (hi + lo ~= v with ~2^-17 rel err)
static __device__ __forceinline__ void split2(float v, ushort& hi, ushort& lo) {
  hi = f2bf(v);
  lo = f2bf(v - bf1(hi));
}

// ---------------- edge sort (counting sort by dst) ----------------

__global__ void hist_kernel(const int* __restrict__ dst, int* __restrict__ hist) {
  int i = blockIdx.x * blockDim.x + threadIdx.x;
  if (i < NE) atomicAdd(&hist[dst[i]], 1);
}

__global__ __launch_bounds__(1024) void scan_kernel(const int* __restrict__ hist,
                                                    int* __restrict__ offs,
                                                    int* __restrict__ cursor) {
  __shared__ int sdata[1024];
  __shared__ int srun;
  int tid = threadIdx.x;
  if (tid == 0) srun = 0;
  __syncthreads();
  for (int base = 0; base < NN; base += 1024) {
    int i = base + tid;
    int v = (i < NN) ? hist[i] : 0;
    sdata[tid] = v;
    __syncthreads();
    for (int ofs = 1; ofs < 1024; ofs <<= 1) {
      int t = (tid >= ofs) ? sdata[tid - ofs] : 0;
      __syncthreads();
      sdata[tid] += t;
      __syncthreads();
    }
    int run = srun;
    __syncthreads();
    if (i < NN) {
      int excl = run + sdata[tid] - v;
      offs[i] = excl;
      cursor[i] = excl;
    }
    if (tid == 0) srun = run + sdata[1023];
    __syncthreads();
  }
  if (tid == 0) offs[NN] = srun;
}

__global__ void scatter_kernel(const int* __restrict__ src, const int* __restrict__ dst,
                               const float* __restrict__ w, int* __restrict__ cursor,
                               int* __restrict__ ssrc, float* __restrict__ sw) {
  int i = blockIdx.x * blockDim.x + threadIdx.x;
  if (i < NE) {
    int d = dst[i];
    int p = atomicAdd(&cursor[d], 1);
    ssrc[p] = src[i];
    sw[p]   = w[i];
  }
}

// ---------------- pad zeroing for pair buffers ----------------
// zero rows [NN,MP) fully and cols [Ntrue,KPAD) for rows [0,NN)

__global__ void padzero_kernel(ushort* __restrict__ bh, ushort* __restrict__ bl,
                               int KPAD, int Ntrue) {
  long long nA = (long long)(MP - NN) * KPAD;
  int padc = KPAD - Ntrue;
  long long nB = (long long)NN * padc;
  long long total = nA + nB;
  long long stride = (long long)gridDim.x * blockDim.x;
  for (long long i = blockIdx.x * (long long)blockDim.x + threadIdx.x; i < total; i += stride) {
    long long off;
    if (i < nA) {
      off = (long long)NN * KPAD + i;
    } else {
      long long j = i - nA;
      long long r = j / padc;
      long long c = Ntrue + (j - r * padc);
      off = r * KPAD + c;
    }
    bh[off] = 0;
    bl[off] = 0;
  }
}

// ---------------- weight pre-pack (hi only): Bp[n][k] = bf16(W[k][n]) ----------------

__global__ void packW1_kernel(const float* __restrict__ W1s, ushort* __restrict__ Wh) {
  int idx = blockIdx.x * blockDim.x + threadIdx.x;
  if (idx >= NL * NP1 * KP1) return;
  int i = idx / (NP1 * KP1);
  int rem = idx - i * (NP1 * KP1);
  int n = rem / KP1;
  int k = rem - n * KP1;
  float v = (n < H2 && k < H) ? W1s[((long long)i * H + k) * H2 + n] : 0.f;
  Wh[idx] = f2bf(v);
}

__global__ void packW2_kernel(const float* __restrict__ W2s, ushort* __restrict__ Wh) {
  int idx = blockIdx.x * blockDim.x + threadIdx.x;
  if (idx >= NL * NP2 * KP2) return;
  int i = idx / (NP2 * KP2);
  int rem = idx - i * (NP2 * KP2);
  int n = rem / KP2;
  int k = rem - n * KP2;
  float v = (n < H && k < H2) ? W2s[((long long)i * H2 + k) * H + n] : 0.f;
  Wh[idx] = f2bf(v);
}

// ---------------- input linear: h = x @ linW + linb (f32 out, stride H) ----------------

__global__ void lin_kernel(const float* __restrict__ x, const float* __restrict__ W,
                           const float* __restrict__ b, float* __restrict__ h) {
  int idx = blockIdx.x * blockDim.x + threadIdx.x;
  if (idx >= NN * H) return;
  int n = idx / H;
  int f = idx - n * H;
  float acc = b[f];
  const float* xr = x + n * IND;
#pragma unroll
  for (int k = 0; k < IND; ++k) acc = fmaf(xr[k], W[k * H + f], acc);
  h[idx] = acc;
}

// ---------------- aggregation: f32 h in, bf16-pair agg out ----------------

__global__ __launch_bounds__(192) void agg_kernel(const float* __restrict__ h,
                                                  const int* __restrict__ offs,
                                                  const int* __restrict__ ssrc,
                                                  const float* __restrict__ sw,
                                                  ushort* __restrict__ aggh,
                                                  ushort* __restrict__ aggl) {
  int n = blockIdx.x;
  int t = threadIdx.x;
  if (t >= H / 2) return;
  int s = offs[n], e = offs[n + 1];
  float a0 = 0.f, a1 = 0.f;
  int i = s;
  for (; i + 1 < e; i += 2) {
    int sn0 = ssrc[i], sn1 = ssrc[i + 1];
    float w0 = sw[i], w1 = sw[i + 1];
    float2 h0 = *reinterpret_cast<const float2*>(h + (long long)sn0 * H + 2 * t);
    float2 h1 = *reinterpret_cast<const float2*>(h + (long long)sn1 * H + 2 * t);
    a0 = fmaf(w0, h0.x, a0);
    a1 = fmaf(w0, h0.y, a1);
    a0 = fmaf(w1, h1.x, a0);
    a1 = fmaf(w1, h1.y, a1);
  }
  if (i < e) {
    int sn = ssrc[i];
    float w = sw[i];
    float2 hv = *reinterpret_cast<const float2*>(h + (long long)sn * H + 2 * t);
    a0 = fmaf(w, hv.x, a0);
    a1 = fmaf(w, hv.y, a1);
  }
  ushort h0, l0, h1, l1;
  split2(a0, h0, l0);
  split2(a1, h1, l1);
  long long base = (long long)n * KP1 + 2 * t;
  *reinterpret_cast<uint32_t*>(aggh + base) = (uint32_t)h0 | ((uint32_t)h1 << 16);
  *reinterpret_cast<uint32_t*>(aggl + base) = (uint32_t)l0 | ((uint32_t)l1 << 16);
}

// ---------------- split-precision bf16 MFMA GEMM, fused column stats ----------------
// C = (Ah+Al) @ Bh^T_packed + bias (2-term: al*bh + ah*bh)
// A: [MP][KPAD] pairs. Bh: [Npad][KPAD] bf16 (Bh[n][k] = bf16(B[k][n])).
// C written as bf16 pairs; column sum / sumsq accumulated via atomics.

__global__ __launch_bounds__(256) void gemm_mfma(
    const ushort* __restrict__ Ah, const ushort* __restrict__ Al,
    const ushort* __restrict__ Bh, const float* __restrict__ bias,
    ushort* __restrict__ Ch, ushort* __restrict__ Cl,
    float* __restrict__ sum, float* __restrict__ sq,
    int M, int Ntrue, int Ktiles, int KPAD, int Cstride) {
  int tid = threadIdx.x;
  int lane = tid & 63, wid = tid >> 6;
  int wm = wid >> 1, wn = wid & 1;
  int lm = lane & 15, lg = lane >> 4;
  long long bm = (long long)blockIdx.x * 128;
  long long bn = (long long)blockIdx.y * 128;

  long long aoff = (bm + wm * 64 + lm) * KPAD + lg * 8;
  long long boff = (bn + wn * 64 + lm) * KPAD + lg * 8;
  const ushort* Abh = Ah + aoff;
  const ushort* Abl = Al + aoff;
  const ushort* Bbh = Bh + boff;

  f32x4 acc[4][4] = {};

  for (int kt = 0; kt < Ktiles; ++kt) {
    int ko = kt * 32;
    bf16x8 ah[4], al[4], bh[4];
#pragma unroll
    for (int i = 0; i < 4; ++i) {
      long long o = (long long)i * 16 * KPAD + ko;
      ah[i] = *reinterpret_cast<const bf16x8*>(Abh + o);
      al[i] = *reinterpret_cast<const bf16x8*>(Abl + o);
      bh[i] = *reinterpret_cast<const bf16x8*>(Bbh + o);
    }
#pragma unroll
    for (int mf = 0; mf < 4; ++mf)
#pragma unroll
      for (int nf = 0; nf < 4; ++nf) {
        acc[mf][nf] = __builtin_amdgcn_mfma_f32_16x16x32_bf16(al[mf], bh[nf], acc[mf][nf], 0, 0, 0);
        acc[mf][nf] = __builtin_amdgcn_mfma_f32_16x16x32_bf16(ah[mf], bh[nf], acc[mf][nf], 0, 0, 0);
      }
  }

  int colb = (int)bn + wn * 64 + lm;
#pragma unroll
  for (int nf = 0; nf < 4; ++nf) {
    int col = colb + nf * 16;
    bool cok = col < Ntrue;
    float bv = cok ? bias[col] : 0.f;
    float cs = 0.f, cq = 0.f;
#pragma unroll
    for (int mf = 0; mf < 4; ++mf) {
      int row = (int)bm + wm * 64 + mf * 16 + lg * 4;
      f32x4 v = acc[mf][nf];
#pragma unroll
      for (int e = 0; e < 4; ++e) {
        if (cok && row + e < M) {
          float w = v[e] + bv;
          cs += w;
          cq = fmaf(w, w, cq);
          ushort hi, lo;
          split2(w, hi, lo);
          long long o = (long long)(row + e) * Cstride + col;
          Ch[o] = hi;
          Cl[o] = lo;
        }
      }
    }
    // reduce across the 4 lg groups (lanes lane^16, lane^32 share col)
    cs += __shfl_xor(cs, 16);
    cq += __shfl_xor(cq, 16);
    cs += __shfl_xor(cs, 32);
    cq += __shfl_xor(cq, 32);
    if (lg == 0 && cok) {
      atomicAdd(&sum[col], cs);
      atomicAdd(&sq[col], cq);
    }
  }
}

// ---------------- BN finalize ----------------

__global__ void finalize_kernel(const float* __restrict__ sum, const float* __restrict__ sq,
                                const float* __restrict__ g, const float* __restrict__ be,
                                int C, float invM, float* __restrict__ scale,
                                float* __restrict__ shift) {
  int c = blockIdx.x * blockDim.x + threadIdx.x;
  if (c < C) {
    float m = sum[c] * invM;
    float v = sq[c] * invM - m * m;
    float sc = g[c] * rsqrtf(v + 1e-5f);
    scale[c] = sc;
    shift[c] = be[c] - m * sc;
  }
}

// ---------------- BN apply ----------------
// bn1: in-place on t pairs (stride KP2), relu, re-split
__global__ void bn1_kernel(ushort* __restrict__ th_, ushort* __restrict__ tl_,
                           const float* __restrict__ scale, const float* __restrict__ shift) {
  int idx = blockIdx.x * blockDim.x + threadIdx.x;
  if (idx >= NN * (H2 / 2)) return;
  int r = idx / (H2 / 2);
  int p = idx - r * (H2 / 2);
  int c = 2 * p;
  long long base = (long long)r * KP2 + c;
  uint32_t uh = *reinterpret_cast<uint32_t*>(th_ + base);
  uint32_t ul = *reinterpret_cast<uint32_t*>(tl_ + base);
  float v0 = bflo(uh) + bflo(ul);
  float v1 = bfhi(uh) + bfhi(ul);
  float w0 = fmaxf(fmaf(v0, scale[c], shift[c]), 0.f);
  float w1 = fmaxf(fmaf(v1, scale[c + 1], shift[c + 1]), 0.f);
  ushort h0, l0, h1, l1;
  split2(w0, h0, l0);
  split2(w1, h1, l1);
  *reinterpret_cast<uint32_t*>(th_ + base) = (uint32_t)h0 | ((uint32_t)h1 << 16);
  *reinterpret_cast<uint32_t*>(tl_ + base) = (uint32_t)l0 | ((uint32_t)l1 << 16);
}

// bn2: pairs (stride KP1) -> f32 h (stride H); relu unless LAST
template <bool LAST>
__global__ void bn2_kernel(const ushort* __restrict__ uh_, const ushort* __restrict__ ul_,
                           const float* __restrict__ scale, const float* __restrict__ shift,
                           float* __restrict__ out) {
  int idx = blockIdx.x * blockDim.x + threadIdx.x;
  if (idx >= NN * (H / 2)) return;
  int r = idx / (H / 2);
  int p = idx - r * (H / 2);
  int c = 2 * p;
  long long base = (long long)r * KP1 + c;
  uint32_t uh = *reinterpret_cast<const uint32_t*>(uh_ + base);
  uint32_t ul = *reinterpret_cast<const uint32_t*>(ul_ + base);
  float v0 = bflo(uh) + bflo(ul);
  float v1 = bfhi(uh) + bfhi(ul);
  float w0 = fmaf(v0, scale[c], shift[c]);
  float w1 = fmaf(v1, scale[c + 1], shift[c + 1]);
  if (!LAST) {
    w0 = fmaxf(w0, 0.f);
    w1 = fmaxf(w1, 0.f);
  }
  float2 wv = make_float2(w0, w1);
  *reinterpret_cast<float2*>(out + (long long)r * H + c) = wv;
}

// ---------------- graph pooling ----------------

__global__ void bounds_kernel(const int* __restrict__ batch, int* __restrict__ gstart) {
  int g = threadIdx.x;
  if (g > NG) return;
  if (g == NG) { gstart[NG] = NN; return; }
  int lo = 0, hi = NN;
  while (lo < hi) {
    int mid = (lo + hi) >> 1;
    if (batch[mid] < g) lo = mid + 1; else hi = mid;
  }
  gstart[g] = lo;
}

__global__ __launch_bounds__(320) void pool_kernel(const float* __restrict__ h,
                                                   const int* __restrict__ gstart,
                                                   float* __restrict__ xpool) {
  int g = blockIdx.x;
  int f = threadIdx.x;
  if (f >= H) return;
  int s = gstart[g], e = gstart[g + 1];
  float acc = 0.f;
  for (int r = s + blockIdx.y; r < e; r += gridDim.y) acc += h[(long long)r * H + f];
  atomicAdd(&xpool[g * H + f], acc);
}

// ---------------- driver ----------------

extern "C" void kernel_launch(void* const* d_in, const int* in_sizes, int n_in,
                              void* d_out, int out_size, void* d_ws, size_t ws_size,
                              hipStream_t stream) {
  const int*   batch = (const int*)d_in[0];
  const float* x     = (const float*)d_in[1];
  const int*   eidx  = (const int*)d_in[2];
  const float* eattr = (const float*)d_in[3];
  const float* linW  = (const float*)d_in[4];
  const float* linb  = (const float*)d_in[5];
  const float* W1s   = (const float*)d_in[6];
  const float* b1s   = (const float*)d_in[7];
  const float* g1s   = (const float*)d_in[8];
  const float* be1s  = (const float*)d_in[9];
  const float* W2s   = (const float*)d_in[10];
  const float* b2s   = (const float*)d_in[11];
  const float* gos   = (const float*)d_in[12];
  const float* bos   = (const float*)d_in[13];

  const int* esrc = eidx;
  const int* edst = eidx + NE;

  char* p = (char*)d_ws;
  auto alloc = [&](size_t bytes) {
    char* r = p;
    p += (bytes + 255) & ~(size_t)255;
    return r;
  };
  ushort* th   = (ushort*)alloc((size_t)MP * KP2 * 2);   // t pairs (then t' pairs)
  ushort* tl   = (ushort*)alloc((size_t)MP * KP2 * 2);
  ushort* aggh = (ushort*)alloc((size_t)MP * KP1 * 2);   // agg pairs; reused as u pairs
  ushort* aggl = (ushort*)alloc((size_t)MP * KP1 * 2);
  ushort* W1h  = (ushort*)alloc((size_t)NL * NP1 * KP1 * 2);
  ushort* W2h  = (ushort*)alloc((size_t)NL * NP2 * KP2 * 2);
  int*    hist   = (int*)alloc((size_t)NN * 4);
  int*    offs   = (int*)alloc((size_t)(NN + 64) * 4);
  int*    cursor = (int*)alloc((size_t)NN * 4);
  int*    ssrc   = (int*)alloc((size_t)NE * 4);
  float*  sw     = (float*)alloc((size_t)NE * 4);
  float*  sum1   = (float*)alloc((size_t)(H2 * 2 + H * 2) * 4);
  float*  sq1    = sum1 + H2;
  float*  sum2   = sq1 + H2;
  float*  sq2    = sum2 + H;
  float*  scale1 = (float*)alloc((size_t)(H2 * 2 + H * 2) * 4);
  float*  shift1 = scale1 + H2;
  float*  scale2 = shift1 + H2;
  float*  shift2 = scale2 + H;
  int*    gstart = (int*)alloc((size_t)(NG + 1) * 4);
  size_t needed = (size_t)(p - (char*)d_ws);
  if (ws_size < needed) return;

  float* hout  = (float*)d_out;               // also the inter-layer f32 h buffer
  float* xpool = hout + (long long)NN * H;

  // zero the MFMA pad regions of the pair buffers
  padzero_kernel<<<1024, 256, 0, stream>>>(th, tl, KP2, H2);
  padzero_kernel<<<1024, 256, 0, stream>>>(aggh, aggl, KP1, H);

  // weight pre-pack (hi only)
  packW1_kernel<<<(NL * NP1 * KP1 + 255) / 256, 256, 0, stream>>>(W1s, W1h);
  packW2_kernel<<<(NL * NP2 * KP2 + 255) / 256, 256, 0, stream>>>(W2s, W2h);

  // edge sort
  hipMemsetAsync(hist, 0, (size_t)NN * 4, stream);
  hist_kernel<<<(NE + 255) / 256, 256, 0, stream>>>(edst, hist);
  scan_kernel<<<1, 1024, 0, stream>>>(hist, offs, cursor);
  scatter_kernel<<<(NE + 255) / 256, 256, 0, stream>>>(esrc, edst, eattr, cursor, ssrc, sw);

  // h0 = x @ linW + linb (f32, into hout)
  lin_kernel<<<(NN * H + 255) / 256, 256, 0, stream>>>(x, linW, linb, hout);

  for (int i = 0; i < NL; ++i) {
    agg_kernel<<<NN, 192, 0, stream>>>(hout, offs, ssrc, sw, aggh, aggl);
    hipMemsetAsync(sum1, 0, (size_t)(H2 * 2 + H * 2) * 4, stream);

    // t = agg @ W1 + b1  (pairs out, stats fused)
    gemm_mfma<<<dim3(MP / 128, NP1 / 128), 256, 0, stream>>>(
        aggh, aggl, W1h + (size_t)i * NP1 * KP1, b1s + (size_t)i * H2, th, tl,
        sum1, sq1, NN, H2, KP1 / 32, KP1, KP2);
    finalize_kernel<<<(H2 + 255) / 256, 256, 0, stream>>>(sum1, sq1, g1s + (size_t)i * H2,
                                                          be1s + (size_t)i * H2, H2, 1.f / NN,
                                                          scale1, shift1);
    bn1_kernel<<<(NN * (H2 / 2) + 255) / 256, 256, 0, stream>>>(th, tl, scale1, shift1);

    // u = t' @ W2 + b2 (pairs into aggh/aggl, stride KP1, stats fused)
    gemm_mfma<<<dim3(MP / 128, NP2 / 128), 256, 0, stream>>>(
        th, tl, W2h + (size_t)i * NP2 * KP2, b2s + (size_t)i * H, aggh, aggl,
        sum2, sq2, NN, H, KP2 / 32, KP2, KP1);
    finalize_kernel<<<1, 512, 0, stream>>>(sum2, sq2, gos + (size_t)i * H, bos + (size_t)i * H, H,
                                           1.f / NN, scale2, shift2);
    if (i < NL - 1) {
      bn2_kernel<false><<<(NN * (H / 2) + 255) / 256, 256, 0, stream>>>(aggh, aggl, scale2,
                                                                        shift2, hout);
    } else {
      bn2_kernel<true><<<(NN * (H / 2) + 255) / 256, 256, 0, stream>>>(aggh, aggl, scale2,
                                                                       shift2, hout);
    }
  }

  // pooling
  hipMemsetAsync(xpool, 0, (size_t)NG * H * 4, stream);
  bounds_kernel<<<1, 128, 0, stream>>>(batch, gstart);
  pool_kernel<<<dim3(NG, 8), 320, 0, stream>>>(hout, gstart, xpool);
}

// Round 5
// 2507.253 us; speedup vs baseline: 2.2350x; 1.3139x over previous
//
#include <hip/hip_runtime.h>
#include <stdint.h>

typedef __bf16 bf16x8 __attribute__((ext_vector_type(8)));
typedef float f32x4 __attribute__((ext_vector_type(4)));

constexpr int NN  = 50000;   // nodes
constexpr int NE  = 800000;  // edges
constexpr int NG  = 64;      // graphs
constexpr int H   = 300;     // hidden
constexpr int H2  = 600;     // 2*hidden
constexpr int IND = 20;      // 2*PERIOD
constexpr int NL  = 5;

constexpr int MP  = 50048;   // rows padded to multiple of 128
constexpr int KP1 = 320;     // padded K stride for agg/u buffers (mult of 32)
constexpr int KP2 = 608;     // padded K stride for t buffers (mult of 32)
constexpr int NP1 = 640;     // padded N for gemm1 (5 x 128)
constexpr int NP2 = 384;     // padded N for gemm2 (3 x 128)

// ---------------- bf16 helpers (RNE) + split-precision ----------------
static __device__ __forceinline__ ushort f2bf(float f) {
  uint32_t u = __float_as_uint(f);
  return (ushort)((u + 0x7FFFu + ((u >> 16) & 1u)) >> 16);
}
static __device__ __forceinline__ float bf1(ushort s) { return __uint_as_float((uint32_t)s << 16); }
static __device__ __forceinline__ float bflo(uint32_t u) { return __uint_as_float(u << 16); }
static __device__ __forceinline__ float bfhi(uint32_t u) { return __uint_as_float(u & 0xFFFF0000u); }
static __device__ __forceinline__ void split2(float v, ushort& hi, ushort& lo) {
  hi = f2bf(v);
  lo = f2bf(v - bf1(hi));
}

// ---------------- edge sort (counting sort by dst) ----------------

__global__ void hist_kernel(const int* __restrict__ dst, int* __restrict__ hist) {
  int i = blockIdx.x * blockDim.x + threadIdx.x;
  if (i < NE) atomicAdd(&hist[dst[i]], 1);
}

__global__ __launch_bounds__(1024) void scan_kernel(const int* __restrict__ hist,
                                                    int* __restrict__ offs,
                                                    int* __restrict__ cursor) {
  __shared__ int sdata[1024];
  __shared__ int srun;
  int tid = threadIdx.x;
  if (tid == 0) srun = 0;
  __syncthreads();
  for (int base = 0; base < NN; base += 1024) {
    int i = base + tid;
    int v = (i < NN) ? hist[i] : 0;
    sdata[tid] = v;
    __syncthreads();
    for (int ofs = 1; ofs < 1024; ofs <<= 1) {
      int t = (tid >= ofs) ? sdata[tid - ofs] : 0;
      __syncthreads();
      sdata[tid] += t;
      __syncthreads();
    }
    int run = srun;
    __syncthreads();
    if (i < NN) {
      int excl = run + sdata[tid] - v;
      offs[i] = excl;
      cursor[i] = excl;
    }
    if (tid == 0) srun = run + sdata[1023];
    __syncthreads();
  }
  if (tid == 0) offs[NN] = srun;
}

__global__ void scatter_kernel(const int* __restrict__ src, const int* __restrict__ dst,
                               const float* __restrict__ w, int* __restrict__ cursor,
                               int* __restrict__ ssrc, float* __restrict__ sw) {
  int i = blockIdx.x * blockDim.x + threadIdx.x;
  if (i < NE) {
    int d = dst[i];
    int p = atomicAdd(&cursor[d], 1);
    ssrc[p] = src[i];
    sw[p]   = w[i];
  }
}

// ---------------- pad zeroing for pair buffers ----------------

__global__ void padzero_kernel(ushort* __restrict__ bh, ushort* __restrict__ bl,
                               int KPAD, int Ntrue) {
  long long nA = (long long)(MP - NN) * KPAD;
  int padc = KPAD - Ntrue;
  long long nB = (long long)NN * padc;
  long long total = nA + nB;
  long long stride = (long long)gridDim.x * blockDim.x;
  for (long long i = blockIdx.x * (long long)blockDim.x + threadIdx.x; i < total; i += stride) {
    long long off;
    if (i < nA) {
      off = (long long)NN * KPAD + i;
    } else {
      long long j = i - nA;
      long long r = j / padc;
      long long c = Ntrue + (j - r * padc);
      off = r * KPAD + c;
    }
    bh[off] = 0;
    bl[off] = 0;
  }
}

// ---------------- weight pre-pack (hi only): Bp[n][k] = bf16(W[k][n]) ----------------

__global__ void packW1_kernel(const float* __restrict__ W1s, ushort* __restrict__ Wh) {
  int idx = blockIdx.x * blockDim.x + threadIdx.x;
  if (idx >= NL * NP1 * KP1) return;
  int i = idx / (NP1 * KP1);
  int rem = idx - i * (NP1 * KP1);
  int n = rem / KP1;
  int k = rem - n * KP1;
  float v = (n < H2 && k < H) ? W1s[((long long)i * H + k) * H2 + n] : 0.f;
  Wh[idx] = f2bf(v);
}

__global__ void packW2_kernel(const float* __restrict__ W2s, ushort* __restrict__ Wh) {
  int idx = blockIdx.x * blockDim.x + threadIdx.x;
  if (idx >= NL * NP2 * KP2) return;
  int i = idx / (NP2 * KP2);
  int rem = idx - i * (NP2 * KP2);
  int n = rem / KP2;
  int k = rem - n * KP2;
  float v = (n < H && k < H2) ? W2s[((long long)i * H2 + k) * H + n] : 0.f;
  Wh[idx] = f2bf(v);
}

// ---------------- input linear: h = x @ linW + linb (f32 out, stride H) ----------------

__global__ void lin_kernel(const float* __restrict__ x, const float* __restrict__ W,
                           const float* __restrict__ b, float* __restrict__ h) {
  int idx = blockIdx.x * blockDim.x + threadIdx.x;
  if (idx >= NN * H) return;
  int n = idx / H;
  int f = idx - n * H;
  float acc = b[f];
  const float* xr = x + n * IND;
#pragma unroll
  for (int k = 0; k < IND; ++k) acc = fmaf(xr[k], W[k * H + f], acc);
  h[idx] = acc;
}

// ---------------- aggregation: f32 h in, bf16-pair agg out ----------------

__global__ __launch_bounds__(192) void agg_kernel(const float* __restrict__ h,
                                                  const int* __restrict__ offs,
                                                  const int* __restrict__ ssrc,
                                                  const float* __restrict__ sw,
                                                  ushort* __restrict__ aggh,
                                                  ushort* __restrict__ aggl) {
  int n = blockIdx.x;
  int t = threadIdx.x;
  if (t >= H / 2) return;
  int s = offs[n], e = offs[n + 1];
  float a0 = 0.f, a1 = 0.f;
  int i = s;
  for (; i + 1 < e; i += 2) {
    int sn0 = ssrc[i], sn1 = ssrc[i + 1];
    float w0 = sw[i], w1 = sw[i + 1];
    float2 h0 = *reinterpret_cast<const float2*>(h + (long long)sn0 * H + 2 * t);
    float2 h1 = *reinterpret_cast<const float2*>(h + (long long)sn1 * H + 2 * t);
    a0 = fmaf(w0, h0.x, a0);
    a1 = fmaf(w0, h0.y, a1);
    a0 = fmaf(w1, h1.x, a0);
    a1 = fmaf(w1, h1.y, a1);
  }
  if (i < e) {
    int sn = ssrc[i];
    float w = sw[i];
    float2 hv = *reinterpret_cast<const float2*>(h + (long long)sn * H + 2 * t);
    a0 = fmaf(w, hv.x, a0);
    a1 = fmaf(w, hv.y, a1);
  }
  ushort h0, l0, h1, l1;
  split2(a0, h0, l0);
  split2(a1, h1, l1);
  long long base = (long long)n * KP1 + 2 * t;
  *reinterpret_cast<uint32_t*>(aggh + base) = (uint32_t)h0 | ((uint32_t)h1 << 16);
  *reinterpret_cast<uint32_t*>(aggl + base) = (uint32_t)l0 | ((uint32_t)l1 << 16);
}

// ---------------- split-precision MFMA GEMM, LDS-staged A, fused column stats ----------------
// C = (Ah+Al) @ Bh^T_packed + bias (2-term). A staged via global_load_lds (dbuf, BK=32,
// XOR-swizzled chunks); B register-double-buffered from L2. Grid: x = N-tile (A reuse).

__global__ __launch_bounds__(256, 3) void gemm_mfma(
    const ushort* __restrict__ Ah, const ushort* __restrict__ Al,
    const ushort* __restrict__ Bh, const float* __restrict__ bias,
    ushort* __restrict__ Ch, ushort* __restrict__ Cl,
    float* __restrict__ sum, float* __restrict__ sq,
    int M, int Ntrue, int Ktiles, int KPAD, int Cstride) {
  __shared__ ushort AhL[2][128 * 32];
  __shared__ ushort AlL[2][128 * 32];
  int tid = threadIdx.x;
  int lane = tid & 63, wid = tid >> 6;
  int wm = wid >> 1, wn = wid & 1;
  int lm = lane & 15, lg = lane >> 4;
  long long bm = (long long)blockIdx.y * 128;
  long long bn = (long long)blockIdx.x * 128;

  int srow = lane >> 2;   // 0..15 row within this wave's 16-row staging segment
  int slot = lane & 3;    // LDS chunk slot (8 bf16 per chunk)

  const ushort* Bb = Bh + (bn + wn * 64 + lm) * KPAD + lg * 8;

  f32x4 acc[4][4] = {};

  auto stageA = [&](int buf, int kt) {
    int k0 = kt * 32;
#pragma unroll
    for (int j = 0; j < 2; ++j) {
      int row = j * 64 + wid * 16 + srow;                 // row in 128-tile
      int cg = slot ^ ((row >> 1) & 3);                   // swizzled source chunk
      long long go = (bm + row) * KPAD + k0 + cg * 8;
      ushort* lh = &AhL[buf][(j * 64 + wid * 16) * 32];   // wave-uniform base
      ushort* ll = &AlL[buf][(j * 64 + wid * 16) * 32];
      __builtin_amdgcn_global_load_lds(
          (const __attribute__((address_space(1))) void*)(Ah + go),
          (__attribute__((address_space(3))) void*)lh, 16, 0, 0);
      __builtin_amdgcn_global_load_lds(
          (const __attribute__((address_space(1))) void*)(Al + go),
          (__attribute__((address_space(3))) void*)ll, 16, 0, 0);
    }
  };

  bf16x8 bcur[4], bnxt[4];
  stageA(0, 0);
#pragma unroll
  for (int i = 0; i < 4; ++i)
    bcur[i] = *reinterpret_cast<const bf16x8*>(Bb + (long long)i * 16 * KPAD);
  __syncthreads();

  for (int kt = 0; kt < Ktiles; ++kt) {
    int cur = kt & 1;
    int nk = kt + 1;
    if (nk < Ktiles) {
      stageA(nk & 1, nk);
#pragma unroll
      for (int i = 0; i < 4; ++i)
        bnxt[i] = *reinterpret_cast<const bf16x8*>(Bb + (long long)i * 16 * KPAD + nk * 32);
    }
    bf16x8 ah[4], al[4];
#pragma unroll
    for (int i = 0; i < 4; ++i) {
      int row = wm * 64 + i * 16 + lm;
      int c = lg ^ ((row >> 1) & 3);
      ah[i] = *reinterpret_cast<const bf16x8*>(&AhL[cur][row * 32 + c * 8]);
      al[i] = *reinterpret_cast<const bf16x8*>(&AlL[cur][row * 32 + c * 8]);
    }
#pragma unroll
    for (int mf = 0; mf < 4; ++mf)
#pragma unroll
      for (int nf = 0; nf < 4; ++nf) {
        acc[mf][nf] = __builtin_amdgcn_mfma_f32_16x16x32_bf16(al[mf], bcur[nf], acc[mf][nf], 0, 0, 0);
        acc[mf][nf] = __builtin_amdgcn_mfma_f32_16x16x32_bf16(ah[mf], bcur[nf], acc[mf][nf], 0, 0, 0);
      }
    __syncthreads();
#pragma unroll
    for (int i = 0; i < 4; ++i) bcur[i] = bnxt[i];
  }

  int colb = (int)bn + wn * 64 + lm;
#pragma unroll
  for (int nf = 0; nf < 4; ++nf) {
    int col = colb + nf * 16;
    bool cok = col < Ntrue;
    float bv = cok ? bias[col] : 0.f;
    float cs = 0.f, cq = 0.f;
#pragma unroll
    for (int mf = 0; mf < 4; ++mf) {
      int row = (int)bm + wm * 64 + mf * 16 + lg * 4;
      f32x4 v = acc[mf][nf];
#pragma unroll
      for (int e = 0; e < 4; ++e) {
        if (cok && row + e < M) {
          float w = v[e] + bv;
          cs += w;
          cq = fmaf(w, w, cq);
          ushort hi, lo;
          split2(w, hi, lo);
          long long o = (long long)(row + e) * Cstride + col;
          Ch[o] = hi;
          Cl[o] = lo;
        }
      }
    }
    cs += __shfl_xor(cs, 16);
    cq += __shfl_xor(cq, 16);
    cs += __shfl_xor(cs, 32);
    cq += __shfl_xor(cq, 32);
    if (lg == 0 && cok) {
      atomicAdd(&sum[col], cs);
      atomicAdd(&sq[col], cq);
    }
  }
}

// ---------------- BN finalize ----------------

__global__ void finalize_kernel(const float* __restrict__ sum, const float* __restrict__ sq,
                                const float* __restrict__ g, const float* __restrict__ be,
                                int C, float invM, float* __restrict__ scale,
                                float* __restrict__ shift) {
  int c = blockIdx.x * blockDim.x + threadIdx.x;
  if (c < C) {
    float m = sum[c] * invM;
    float v = sq[c] * invM - m * m;
    float sc = g[c] * rsqrtf(v + 1e-5f);
    scale[c] = sc;
    shift[c] = be[c] - m * sc;
  }
}

// ---------------- BN apply ----------------

__global__ void bn1_kernel(ushort* __restrict__ th_, ushort* __restrict__ tl_,
                           const float* __restrict__ scale, const float* __restrict__ shift) {
  int idx = blockIdx.x * blockDim.x + threadIdx.x;
  if (idx >= NN * (H2 / 2)) return;
  int r = idx / (H2 / 2);
  int p = idx - r * (H2 / 2);
  int c = 2 * p;
  long long base = (long long)r * KP2 + c;
  uint32_t uh = *reinterpret_cast<uint32_t*>(th_ + base);
  uint32_t ul = *reinterpret_cast<uint32_t*>(tl_ + base);
  float v0 = bflo(uh) + bflo(ul);
  float v1 = bfhi(uh) + bfhi(ul);
  float w0 = fmaxf(fmaf(v0, scale[c], shift[c]), 0.f);
  float w1 = fmaxf(fmaf(v1, scale[c + 1], shift[c + 1]), 0.f);
  ushort h0, l0, h1, l1;
  split2(w0, h0, l0);
  split2(w1, h1, l1);
  *reinterpret_cast<uint32_t*>(th_ + base) = (uint32_t)h0 | ((uint32_t)h1 << 16);
  *reinterpret_cast<uint32_t*>(tl_ + base) = (uint32_t)l0 | ((uint32_t)l1 << 16);
}

template <bool LAST>
__global__ void bn2_kernel(const ushort* __restrict__ uh_, const ushort* __restrict__ ul_,
                           const float* __restrict__ scale, const float* __restrict__ shift,
                           float* __restrict__ out) {
  int idx = blockIdx.x * blockDim.x + threadIdx.x;
  if (idx >= NN * (H / 2)) return;
  int r = idx / (H / 2);
  int p = idx - r * (H / 2);
  int c = 2 * p;
  long long base = (long long)r * KP1 + c;
  uint32_t uh = *reinterpret_cast<const uint32_t*>(uh_ + base);
  uint32_t ul = *reinterpret_cast<const uint32_t*>(ul_ + base);
  float v0 = bflo(uh) + bflo(ul);
  float v1 = bfhi(uh) + bfhi(ul);
  float w0 = fmaf(v0, scale[c], shift[c]);
  float w1 = fmaf(v1, scale[c + 1], shift[c + 1]);
  if (!LAST) {
    w0 = fmaxf(w0, 0.f);
    w1 = fmaxf(w1, 0.f);
  }
  float2 wv = make_float2(w0, w1);
  *reinterpret_cast<float2*>(out + (long long)r * H + c) = wv;
}

// ---------------- graph pooling ----------------

__global__ void bounds_kernel(const int* __restrict__ batch, int* __restrict__ gstart) {
  int g = threadIdx.x;
  if (g > NG) return;
  if (g == NG) { gstart[NG] = NN; return; }
  int lo = 0, hi = NN;
  while (lo < hi) {
    int mid = (lo + hi) >> 1;
    if (batch[mid] < g) lo = mid + 1; else hi = mid;
  }
  gstart[g] = lo;
}

__global__ __launch_bounds__(320) void pool_kernel(const float* __restrict__ h,
                                                   const int* __restrict__ gstart,
                                                   float* __restrict__ xpool) {
  int g = blockIdx.x;
  int f = threadIdx.x;
  if (f >= H) return;
  int s = gstart[g], e = gstart[g + 1];
  float acc = 0.f;
  for (int r = s + blockIdx.y; r < e; r += gridDim.y) acc += h[(long long)r * H + f];
  atomicAdd(&xpool[g * H + f], acc);
}

// ---------------- driver ----------------

extern "C" void kernel_launch(void* const* d_in, const int* in_sizes, int n_in,
                              void* d_out, int out_size, void* d_ws, size_t ws_size,
                              hipStream_t stream) {
  const int*   batch = (const int*)d_in[0];
  const float* x     = (const float*)d_in[1];
  const int*   eidx  = (const int*)d_in[2];
  const float* eattr = (const float*)d_in[3];
  const float* linW  = (const float*)d_in[4];
  const float* linb  = (const float*)d_in[5];
  const float* W1s   = (const float*)d_in[6];
  const float* b1s   = (const float*)d_in[7];
  const float* g1s   = (const float*)d_in[8];
  const float* be1s  = (const float*)d_in[9];
  const float* W2s   = (const float*)d_in[10];
  const float* b2s   = (const float*)d_in[11];
  const float* gos   = (const float*)d_in[12];
  const float* bos   = (const float*)d_in[13];

  const int* esrc = eidx;
  const int* edst = eidx + NE;

  char* p = (char*)d_ws;
  auto alloc = [&](size_t bytes) {
    char* r = p;
    p += (bytes + 255) & ~(size_t)255;
    return r;
  };
  ushort* th   = (ushort*)alloc((size_t)MP * KP2 * 2);
  ushort* tl   = (ushort*)alloc((size_t)MP * KP2 * 2);
  ushort* aggh = (ushort*)alloc((size_t)MP * KP1 * 2);
  ushort* aggl = (ushort*)alloc((size_t)MP * KP1 * 2);
  ushort* W1h  = (ushort*)alloc((size_t)NL * NP1 * KP1 * 2);
  ushort* W2h  = (ushort*)alloc((size_t)NL * NP2 * KP2 * 2);
  int*    hist   = (int*)alloc((size_t)NN * 4);
  int*    offs   = (int*)alloc((size_t)(NN + 64) * 4);
  int*    cursor = (int*)alloc((size_t)NN * 4);
  int*    ssrc   = (int*)alloc((size_t)NE * 4);
  float*  sw     = (float*)alloc((size_t)NE * 4);
  float*  sum1   = (float*)alloc((size_t)(H2 * 2 + H * 2) * 4);
  float*  sq1    = sum1 + H2;
  float*  sum2   = sq1 + H2;
  float*  sq2    = sum2 + H;
  float*  scale1 = (float*)alloc((size_t)(H2 * 2 + H * 2) * 4);
  float*  shift1 = scale1 + H2;
  float*  scale2 = shift1 + H2;
  float*  shift2 = scale2 + H;
  int*    gstart = (int*)alloc((size_t)(NG + 1) * 4);
  size_t needed = (size_t)(p - (char*)d_ws);
  if (ws_size < needed) return;

  float* hout  = (float*)d_out;
  float* xpool = hout + (long long)NN * H;

  padzero_kernel<<<1024, 256, 0, stream>>>(th, tl, KP2, H2);
  padzero_kernel<<<1024, 256, 0, stream>>>(aggh, aggl, KP1, H);

  packW1_kernel<<<(NL * NP1 * KP1 + 255) / 256, 256, 0, stream>>>(W1s, W1h);
  packW2_kernel<<<(NL * NP2 * KP2 + 255) / 256, 256, 0, stream>>>(W2s, W2h);

  hipMemsetAsync(hist, 0, (size_t)NN * 4, stream);
  hist_kernel<<<(NE + 255) / 256, 256, 0, stream>>>(edst, hist);
  scan_kernel<<<1, 1024, 0, stream>>>(hist, offs, cursor);
  scatter_kernel<<<(NE + 255) / 256, 256, 0, stream>>>(esrc, edst, eattr, cursor, ssrc, sw);

  lin_kernel<<<(NN * H + 255) / 256, 256, 0, stream>>>(x, linW, linb, hout);

  for (int i = 0; i < NL; ++i) {
    agg_kernel<<<NN, 192, 0, stream>>>(hout, offs, ssrc, sw, aggh, aggl);
    hipMemsetAsync(sum1, 0, (size_t)(H2 * 2 + H * 2) * 4, stream);

    // t = agg @ W1 + b1  (pairs out, stats fused); grid x = N-tiles
    gemm_mfma<<<dim3(NP1 / 128, MP / 128), 256, 0, stream>>>(
        aggh, aggl, W1h + (size_t)i * NP1 * KP1, b1s + (size_t)i * H2, th, tl,
        sum1, sq1, NN, H2, KP1 / 32, KP1, KP2);
    finalize_kernel<<<(H2 + 255) / 256, 256, 0, stream>>>(sum1, sq1, g1s + (size_t)i * H2,
                                                          be1s + (size_t)i * H2, H2, 1.f / NN,
                                                          scale1, shift1);
    bn1_kernel<<<(NN * (H2 / 2) + 255) / 256, 256, 0, stream>>>(th, tl, scale1, shift1);

    // u = t' @ W2 + b2 (pairs into aggh/aggl, stats fused)
    gemm_mfma<<<dim3(NP2 / 128, MP / 128), 256, 0, stream>>>(
        th, tl, W2h + (size_t)i * NP2 * KP2, b2s + (size_t)i * H, aggh, aggl,
        sum2, sq2, NN, H, KP2 / 32, KP2, KP1);
    finalize_kernel<<<1, 512, 0, stream>>>(sum2, sq2, gos + (size_t)i * H, bos + (size_t)i * H, H,
                                           1.f / NN, scale2, shift2);
    if (i < NL - 1) {
      bn2_kernel<false><<<(NN * (H / 2) + 255) / 256, 256, 0, stream>>>(aggh, aggl, scale2,
                                                                        shift2, hout);
    } else {
      bn2_kernel<true><<<(NN * (H / 2) + 255) / 256, 256, 0, stream>>>(aggh, aggl, scale2,
                                                                       shift2, hout);
    }
  }

  hipMemsetAsync(xpool, 0, (size_t)NG * H * 4, stream);
  bounds_kernel<<<1, 128, 0, stream>>>(batch, gstart);
  pool_kernel<<<dim3(NG, 8), 320, 0, stream>>>(hout, gstart, xpool);
}

// Round 6
// 2222.679 us; speedup vs baseline: 2.5212x; 1.1280x over previous
//
#include <hip/hip_runtime.h>
#include <hip/hip_fp16.h>
#include <stdint.h>

typedef __bf16 bf16x8 __attribute__((ext_vector_type(8)));
typedef float f32x4 __attribute__((ext_vector_type(4)));

constexpr int NN  = 50000;   // nodes
constexpr int NE  = 800000;  // edges
constexpr int NG  = 64;      // graphs
constexpr int H   = 300;     // hidden
constexpr int H2  = 600;     // 2*hidden
constexpr int IND = 20;      // 2*PERIOD
constexpr int NL  = 5;

constexpr int MP  = 50048;   // rows padded to multiple of 128
constexpr int KP1 = 320;     // padded K stride for agg/u buffers (mult of 32)
constexpr int KP2 = 608;     // padded K stride for t buffers (mult of 32)
constexpr int NP1 = 640;     // padded N for gemm1 (5 x 128)
constexpr int NP2 = 384;     // padded N for gemm2 (3 x 128)
constexpr int HCS = 320;     // hc (fp16 h copy) row stride

// ---------------- bf16 helpers (RNE) + split-precision ----------------
static __device__ __forceinline__ ushort f2bf(float f) {
  uint32_t u = __float_as_uint(f);
  return (ushort)((u + 0x7FFFu + ((u >> 16) & 1u)) >> 16);
}
static __device__ __forceinline__ float bf1(ushort s) { return __uint_as_float((uint32_t)s << 16); }
static __device__ __forceinline__ float bflo(uint32_t u) { return __uint_as_float(u << 16); }
static __device__ __forceinline__ float bfhi(uint32_t u) { return __uint_as_float(u & 0xFFFF0000u); }
static __device__ __forceinline__ void split2(float v, ushort& hi, ushort& lo) {
  hi = f2bf(v);
  lo = f2bf(v - bf1(hi));
}
// fp16 helpers
static __device__ __forceinline__ ushort f2h(float f) {
  return __half_as_ushort(__float2half(f));
}
static __device__ __forceinline__ float h2f_lo(uint32_t u) {
  return __half2float(__ushort_as_half((ushort)(u & 0xFFFFu)));
}
static __device__ __forceinline__ float h2f_hi(uint32_t u) {
  return __half2float(__ushort_as_half((ushort)(u >> 16)));
}

// ---------------- edge sort (counting sort by dst) ----------------

__global__ void hist_kernel(const int* __restrict__ dst, int* __restrict__ hist) {
  int i = blockIdx.x * blockDim.x + threadIdx.x;
  if (i < NE) atomicAdd(&hist[dst[i]], 1);
}

__global__ __launch_bounds__(1024) void scan_kernel(const int* __restrict__ hist,
                                                    int* __restrict__ offs,
                                                    int* __restrict__ cursor) {
  __shared__ int sdata[1024];
  __shared__ int srun;
  int tid = threadIdx.x;
  if (tid == 0) srun = 0;
  __syncthreads();
  for (int base = 0; base < NN; base += 1024) {
    int i = base + tid;
    int v = (i < NN) ? hist[i] : 0;
    sdata[tid] = v;
    __syncthreads();
    for (int ofs = 1; ofs < 1024; ofs <<= 1) {
      int t = (tid >= ofs) ? sdata[tid - ofs] : 0;
      __syncthreads();
      sdata[tid] += t;
      __syncthreads();
    }
    int run = srun;
    __syncthreads();
    if (i < NN) {
      int excl = run + sdata[tid] - v;
      offs[i] = excl;
      cursor[i] = excl;
    }
    if (tid == 0) srun = run + sdata[1023];
    __syncthreads();
  }
  if (tid == 0) offs[NN] = srun;
}

__global__ void scatter_kernel(const int* __restrict__ src, const int* __restrict__ dst,
                               const float* __restrict__ w, int* __restrict__ cursor,
                               int* __restrict__ ssrc, float* __restrict__ sw) {
  int i = blockIdx.x * blockDim.x + threadIdx.x;
  if (i < NE) {
    int d = dst[i];
    int p = atomicAdd(&cursor[d], 1);
    ssrc[p] = src[i];
    sw[p]   = w[i];
  }
}

// ---------------- pad zeroing for pair buffers ----------------

__global__ void padzero_kernel(ushort* __restrict__ bh, ushort* __restrict__ bl,
                               int KPAD, int Ntrue) {
  long long nA = (long long)(MP - NN) * KPAD;
  int padc = KPAD - Ntrue;
  long long nB = (long long)NN * padc;
  long long total = nA + nB;
  long long stride = (long long)gridDim.x * blockDim.x;
  for (long long i = blockIdx.x * (long long)blockDim.x + threadIdx.x; i < total; i += stride) {
    long long off;
    if (i < nA) {
      off = (long long)NN * KPAD + i;
    } else {
      long long j = i - nA;
      long long r = j / padc;
      long long c = Ntrue + (j - r * padc);
      off = r * KPAD + c;
    }
    bh[off] = 0;
    bl[off] = 0;
  }
}

// ---------------- weight pre-pack (hi only): Bp[n][k] = bf16(W[k][n]) ----------------

__global__ void packW1_kernel(const float* __restrict__ W1s, ushort* __restrict__ Wh) {
  int idx = blockIdx.x * blockDim.x + threadIdx.x;
  if (idx >= NL * NP1 * KP1) return;
  int i = idx / (NP1 * KP1);
  int rem = idx - i * (NP1 * KP1);
  int n = rem / KP1;
  int k = rem - n * KP1;
  float v = (n < H2 && k < H) ? W1s[((long long)i * H + k) * H2 + n] : 0.f;
  Wh[idx] = f2bf(v);
}

__global__ void packW2_kernel(const float* __restrict__ W2s, ushort* __restrict__ Wh) {
  int idx = blockIdx.x * blockDim.x + threadIdx.x;
  if (idx >= NL * NP2 * KP2) return;
  int i = idx / (NP2 * KP2);
  int rem = idx - i * (NP2 * KP2);
  int n = rem / KP2;
  int k = rem - n * KP2;
  float v = (n < H && k < H2) ? W2s[((long long)i * H2 + k) * H + n] : 0.f;
  Wh[idx] = f2bf(v);
}

// ---------------- input linear: hc = fp16(x @ linW + linb), stride HCS ----------------

__global__ void lin_kernel(const float* __restrict__ x, const float* __restrict__ W,
                           const float* __restrict__ b, ushort* __restrict__ hc) {
  int idx = blockIdx.x * blockDim.x + threadIdx.x;
  if (idx >= NN * (H / 2)) return;
  int n = idx / (H / 2);
  int p = idx - n * (H / 2);
  int f = 2 * p;
  float a0 = b[f], a1 = b[f + 1];
  const float* xr = x + n * IND;
#pragma unroll
  for (int k = 0; k < IND; ++k) {
    float xv = xr[k];
    a0 = fmaf(xv, W[k * H + f], a0);
    a1 = fmaf(xv, W[k * H + f + 1], a1);
  }
  *reinterpret_cast<uint32_t*>(hc + (long long)n * HCS + f) =
      (uint32_t)f2h(a0) | ((uint32_t)f2h(a1) << 16);
}

// ---------------- aggregation: fp16 hc gather, bf16-pair agg out ----------------

__global__ __launch_bounds__(192) void agg_kernel(const ushort* __restrict__ hc,
                                                  const int* __restrict__ offs,
                                                  const int* __restrict__ ssrc,
                                                  const float* __restrict__ sw,
                                                  ushort* __restrict__ aggh,
                                                  ushort* __restrict__ aggl) {
  int n = blockIdx.x;
  int t = threadIdx.x;
  if (t >= H / 2) return;
  int s = offs[n], e = offs[n + 1];
  float a0 = 0.f, a1 = 0.f;
  int i = s;
  for (; i + 3 < e; i += 4) {
    int sn0 = ssrc[i], sn1 = ssrc[i + 1], sn2 = ssrc[i + 2], sn3 = ssrc[i + 3];
    float w0 = sw[i], w1 = sw[i + 1], w2 = sw[i + 2], w3 = sw[i + 3];
    uint32_t u0 = *reinterpret_cast<const uint32_t*>(hc + (long long)sn0 * HCS + 2 * t);
    uint32_t u1 = *reinterpret_cast<const uint32_t*>(hc + (long long)sn1 * HCS + 2 * t);
    uint32_t u2 = *reinterpret_cast<const uint32_t*>(hc + (long long)sn2 * HCS + 2 * t);
    uint32_t u3 = *reinterpret_cast<const uint32_t*>(hc + (long long)sn3 * HCS + 2 * t);
    a0 = fmaf(w0, h2f_lo(u0), a0);
    a1 = fmaf(w0, h2f_hi(u0), a1);
    a0 = fmaf(w1, h2f_lo(u1), a0);
    a1 = fmaf(w1, h2f_hi(u1), a1);
    a0 = fmaf(w2, h2f_lo(u2), a0);
    a1 = fmaf(w2, h2f_hi(u2), a1);
    a0 = fmaf(w3, h2f_lo(u3), a0);
    a1 = fmaf(w3, h2f_hi(u3), a1);
  }
  for (; i < e; ++i) {
    int sn = ssrc[i];
    float w = sw[i];
    uint32_t u = *reinterpret_cast<const uint32_t*>(hc + (long long)sn * HCS + 2 * t);
    a0 = fmaf(w, h2f_lo(u), a0);
    a1 = fmaf(w, h2f_hi(u), a1);
  }
  ushort h0, l0, h1, l1;
  split2(a0, h0, l0);
  split2(a1, h1, l1);
  long long base = (long long)n * KP1 + 2 * t;
  *reinterpret_cast<uint32_t*>(aggh + base) = (uint32_t)h0 | ((uint32_t)h1 << 16);
  *reinterpret_cast<uint32_t*>(aggl + base) = (uint32_t)l0 | ((uint32_t)l1 << 16);
}

// ---------------- split-precision MFMA GEMM, LDS-staged A, fused column stats ----------------

__global__ __launch_bounds__(256, 3) void gemm_mfma(
    const ushort* __restrict__ Ah, const ushort* __restrict__ Al,
    const ushort* __restrict__ Bh, const float* __restrict__ bias,
    ushort* __restrict__ Ch, ushort* __restrict__ Cl,
    float* __restrict__ sum, float* __restrict__ sq,
    int M, int Ntrue, int Ktiles, int KPAD, int Cstride) {
  __shared__ ushort AhL[2][128 * 32];
  __shared__ ushort AlL[2][128 * 32];
  int tid = threadIdx.x;
  int lane = tid & 63, wid = tid >> 6;
  int wm = wid >> 1, wn = wid & 1;
  int lm = lane & 15, lg = lane >> 4;
  long long bm = (long long)blockIdx.y * 128;
  long long bn = (long long)blockIdx.x * 128;

  int srow = lane >> 2;
  int slot = lane & 3;

  const ushort* Bb = Bh + (bn + wn * 64 + lm) * KPAD + lg * 8;

  f32x4 acc[4][4] = {};

  auto stageA = [&](int buf, int kt) {
    int k0 = kt * 32;
#pragma unroll
    for (int j = 0; j < 2; ++j) {
      int row = j * 64 + wid * 16 + srow;
      int cg = slot ^ ((row >> 1) & 3);
      long long go = (bm + row) * KPAD + k0 + cg * 8;
      ushort* lh = &AhL[buf][(j * 64 + wid * 16) * 32];
      ushort* ll = &AlL[buf][(j * 64 + wid * 16) * 32];
      __builtin_amdgcn_global_load_lds(
          (const __attribute__((address_space(1))) void*)(Ah + go),
          (__attribute__((address_space(3))) void*)lh, 16, 0, 0);
      __builtin_amdgcn_global_load_lds(
          (const __attribute__((address_space(1))) void*)(Al + go),
          (__attribute__((address_space(3))) void*)ll, 16, 0, 0);
    }
  };

  bf16x8 bcur[4], bnxt[4];
  stageA(0, 0);
#pragma unroll
  for (int i = 0; i < 4; ++i)
    bcur[i] = *reinterpret_cast<const bf16x8*>(Bb + (long long)i * 16 * KPAD);
  __syncthreads();

  for (int kt = 0; kt < Ktiles; ++kt) {
    int cur = kt & 1;
    int nk = kt + 1;
    if (nk < Ktiles) {
      stageA(nk & 1, nk);
#pragma unroll
      for (int i = 0; i < 4; ++i)
        bnxt[i] = *reinterpret_cast<const bf16x8*>(Bb + (long long)i * 16 * KPAD + nk * 32);
    }
    bf16x8 ah[4], al[4];
#pragma unroll
    for (int i = 0; i < 4; ++i) {
      int row = wm * 64 + i * 16 + lm;
      int c = lg ^ ((row >> 1) & 3);
      ah[i] = *reinterpret_cast<const bf16x8*>(&AhL[cur][row * 32 + c * 8]);
      al[i] = *reinterpret_cast<const bf16x8*>(&AlL[cur][row * 32 + c * 8]);
    }
#pragma unroll
    for (int mf = 0; mf < 4; ++mf)
#pragma unroll
      for (int nf = 0; nf < 4; ++nf) {
        acc[mf][nf] = __builtin_amdgcn_mfma_f32_16x16x32_bf16(al[mf], bcur[nf], acc[mf][nf], 0, 0, 0);
        acc[mf][nf] = __builtin_amdgcn_mfma_f32_16x16x32_bf16(ah[mf], bcur[nf], acc[mf][nf], 0, 0, 0);
      }
    __syncthreads();
#pragma unroll
    for (int i = 0; i < 4; ++i) bcur[i] = bnxt[i];
  }

  int colb = (int)bn + wn * 64 + lm;
#pragma unroll
  for (int nf = 0; nf < 4; ++nf) {
    int col = colb + nf * 16;
    bool cok = col < Ntrue;
    float bv = cok ? bias[col] : 0.f;
    float cs = 0.f, cq = 0.f;
#pragma unroll
    for (int mf = 0; mf < 4; ++mf) {
      int row = (int)bm + wm * 64 + mf * 16 + lg * 4;
      f32x4 v = acc[mf][nf];
#pragma unroll
      for (int e = 0; e < 4; ++e) {
        if (cok && row + e < M) {
          float w = v[e] + bv;
          cs += w;
          cq = fmaf(w, w, cq);
          ushort hi, lo;
          split2(w, hi, lo);
          long long o = (long long)(row + e) * Cstride + col;
          Ch[o] = hi;
          Cl[o] = lo;
        }
      }
    }
    cs += __shfl_xor(cs, 16);
    cq += __shfl_xor(cq, 16);
    cs += __shfl_xor(cs, 32);
    cq += __shfl_xor(cq, 32);
    if (lg == 0 && cok) {
      atomicAdd(&sum[col], cs);
      atomicAdd(&sq[col], cq);
    }
  }
}

// ---------------- BN finalize ----------------

__global__ void finalize_kernel(const float* __restrict__ sum, const float* __restrict__ sq,
                                const float* __restrict__ g, const float* __restrict__ be,
                                int C, float invM, float* __restrict__ scale,
                                float* __restrict__ shift) {
  int c = blockIdx.x * blockDim.x + threadIdx.x;
  if (c < C) {
    float m = sum[c] * invM;
    float v = sq[c] * invM - m * m;
    float sc = g[c] * rsqrtf(v + 1e-5f);
    scale[c] = sc;
    shift[c] = be[c] - m * sc;
  }
}

// ---------------- BN apply ----------------

__global__ void bn1_kernel(ushort* __restrict__ th_, ushort* __restrict__ tl_,
                           const float* __restrict__ scale, const float* __restrict__ shift) {
  int idx = blockIdx.x * blockDim.x + threadIdx.x;
  if (idx >= NN * (H2 / 2)) return;
  int r = idx / (H2 / 2);
  int p = idx - r * (H2 / 2);
  int c = 2 * p;
  long long base = (long long)r * KP2 + c;
  uint32_t uh = *reinterpret_cast<uint32_t*>(th_ + base);
  uint32_t ul = *reinterpret_cast<uint32_t*>(tl_ + base);
  float v0 = bflo(uh) + bflo(ul);
  float v1 = bfhi(uh) + bfhi(ul);
  float w0 = fmaxf(fmaf(v0, scale[c], shift[c]), 0.f);
  float w1 = fmaxf(fmaf(v1, scale[c + 1], shift[c + 1]), 0.f);
  ushort h0, l0, h1, l1;
  split2(w0, h0, l0);
  split2(w1, h1, l1);
  *reinterpret_cast<uint32_t*>(th_ + base) = (uint32_t)h0 | ((uint32_t)h1 << 16);
  *reinterpret_cast<uint32_t*>(tl_ + base) = (uint32_t)l0 | ((uint32_t)l1 << 16);
}

// bn2: pairs (stride KP1) -> fp16 hc (intermediate layers) or f32 hout (last layer)
template <bool LAST>
__global__ void bn2_kernel(const ushort* __restrict__ uh_, const ushort* __restrict__ ul_,
                           const float* __restrict__ scale, const float* __restrict__ shift,
                           ushort* __restrict__ hc, float* __restrict__ out) {
  int idx = blockIdx.x * blockDim.x + threadIdx.x;
  if (idx >= NN * (H / 2)) return;
  int r = idx / (H / 2);
  int p = idx - r * (H / 2);
  int c = 2 * p;
  long long base = (long long)r * KP1 + c;
  uint32_t uh = *reinterpret_cast<const uint32_t*>(uh_ + base);
  uint32_t ul = *reinterpret_cast<const uint32_t*>(ul_ + base);
  float v0 = bflo(uh) + bflo(ul);
  float v1 = bfhi(uh) + bfhi(ul);
  float w0 = fmaf(v0, scale[c], shift[c]);
  float w1 = fmaf(v1, scale[c + 1], shift[c + 1]);
  if (LAST) {
    *reinterpret_cast<float2*>(out + (long long)r * H + c) = make_float2(w0, w1);
  } else {
    w0 = fmaxf(w0, 0.f);
    w1 = fmaxf(w1, 0.f);
    *reinterpret_cast<uint32_t*>(hc + (long long)r * HCS + c) =
        (uint32_t)f2h(w0) | ((uint32_t)f2h(w1) << 16);
  }
}

// ---------------- graph pooling ----------------

__global__ void bounds_kernel(const int* __restrict__ batch, int* __restrict__ gstart) {
  int g = threadIdx.x;
  if (g > NG) return;
  if (g == NG) { gstart[NG] = NN; return; }
  int lo = 0, hi = NN;
  while (lo < hi) {
    int mid = (lo + hi) >> 1;
    if (batch[mid] < g) lo = mid + 1; else hi = mid;
  }
  gstart[g] = lo;
}

__global__ __launch_bounds__(320) void pool_kernel(const float* __restrict__ h,
                                                   const int* __restrict__ gstart,
                                                   float* __restrict__ xpool) {
  int g = blockIdx.x;
  int f = threadIdx.x;
  if (f >= H) return;
  int s = gstart[g], e = gstart[g + 1];
  float acc = 0.f;
  for (int r = s + blockIdx.y; r < e; r += gridDim.y) acc += h[(long long)r * H + f];
  atomicAdd(&xpool[g * H + f], acc);
}

// ---------------- driver ----------------

extern "C" void kernel_launch(void* const* d_in, const int* in_sizes, int n_in,
                              void* d_out, int out_size, void* d_ws, size_t ws_size,
                              hipStream_t stream) {
  const int*   batch = (const int*)d_in[0];
  const float* x     = (const float*)d_in[1];
  const int*   eidx  = (const int*)d_in[2];
  const float* eattr = (const float*)d_in[3];
  const float* linW  = (const float*)d_in[4];
  const float* linb  = (const float*)d_in[5];
  const float* W1s   = (const float*)d_in[6];
  const float* b1s   = (const float*)d_in[7];
  const float* g1s   = (const float*)d_in[8];
  const float* be1s  = (const float*)d_in[9];
  const float* W2s   = (const float*)d_in[10];
  const float* b2s   = (const float*)d_in[11];
  const float* gos   = (const float*)d_in[12];
  const float* bos   = (const float*)d_in[13];

  const int* esrc = eidx;
  const int* edst = eidx + NE;

  char* p = (char*)d_ws;
  auto alloc = [&](size_t bytes) {
    char* r = p;
    p += (bytes + 255) & ~(size_t)255;
    return r;
  };
  ushort* th   = (ushort*)alloc((size_t)MP * KP2 * 2);
  ushort* tl   = (ushort*)alloc((size_t)MP * KP2 * 2);
  ushort* aggh = (ushort*)alloc((size_t)MP * KP1 * 2);
  ushort* aggl = (ushort*)alloc((size_t)MP * KP1 * 2);
  ushort* hc   = (ushort*)alloc((size_t)NN * HCS * 2);
  ushort* W1h  = (ushort*)alloc((size_t)NL * NP1 * KP1 * 2);
  ushort* W2h  = (ushort*)alloc((size_t)NL * NP2 * KP2 * 2);
  int*    hist   = (int*)alloc((size_t)NN * 4);
  int*    offs   = (int*)alloc((size_t)(NN + 64) * 4);
  int*    cursor = (int*)alloc((size_t)NN * 4);
  int*    ssrc   = (int*)alloc((size_t)NE * 4);
  float*  sw     = (float*)alloc((size_t)NE * 4);
  float*  sum1   = (float*)alloc((size_t)(H2 * 2 + H * 2) * 4);
  float*  sq1    = sum1 + H2;
  float*  sum2   = sq1 + H2;
  float*  sq2    = sum2 + H;
  float*  scale1 = (float*)alloc((size_t)(H2 * 2 + H * 2) * 4);
  float*  shift1 = scale1 + H2;
  float*  scale2 = shift1 + H2;
  float*  shift2 = scale2 + H;
  int*    gstart = (int*)alloc((size_t)(NG + 1) * 4);
  size_t needed = (size_t)(p - (char*)d_ws);
  if (ws_size < needed) return;

  float* hout  = (float*)d_out;
  float* xpool = hout + (long long)NN * H;

  padzero_kernel<<<1024, 256, 0, stream>>>(th, tl, KP2, H2);
  padzero_kernel<<<1024, 256, 0, stream>>>(aggh, aggl, KP1, H);

  packW1_kernel<<<(NL * NP1 * KP1 + 255) / 256, 256, 0, stream>>>(W1s, W1h);
  packW2_kernel<<<(NL * NP2 * KP2 + 255) / 256, 256, 0, stream>>>(W2s, W2h);

  hipMemsetAsync(hist, 0, (size_t)NN * 4, stream);
  hist_kernel<<<(NE + 255) / 256, 256, 0, stream>>>(edst, hist);
  scan_kernel<<<1, 1024, 0, stream>>>(hist, offs, cursor);
  scatter_kernel<<<(NE + 255) / 256, 256, 0, stream>>>(esrc, edst, eattr, cursor, ssrc, sw);

  lin_kernel<<<(NN * (H / 2) + 255) / 256, 256, 0, stream>>>(x, linW, linb, hc);

  for (int i = 0; i < NL; ++i) {
    agg_kernel<<<NN, 192, 0, stream>>>(hc, offs, ssrc, sw, aggh, aggl);
    hipMemsetAsync(sum1, 0, (size_t)(H2 * 2 + H * 2) * 4, stream);

    // t = agg @ W1 + b1  (pairs out, stats fused); grid x = N-tiles
    gemm_mfma<<<dim3(NP1 / 128, MP / 128), 256, 0, stream>>>(
        aggh, aggl, W1h + (size_t)i * NP1 * KP1, b1s + (size_t)i * H2, th, tl,
        sum1, sq1, NN, H2, KP1 / 32, KP1, KP2);
    finalize_kernel<<<(H2 + 255) / 256, 256, 0, stream>>>(sum1, sq1, g1s + (size_t)i * H2,
                                                          be1s + (size_t)i * H2, H2, 1.f / NN,
                                                          scale1, shift1);
    bn1_kernel<<<(NN * (H2 / 2) + 255) / 256, 256, 0, stream>>>(th, tl, scale1, shift1);

    // u = t' @ W2 + b2 (pairs into aggh/aggl, stats fused)
    gemm_mfma<<<dim3(NP2 / 128, MP / 128), 256, 0, stream>>>(
        th, tl, W2h + (size_t)i * NP2 * KP2, b2s + (size_t)i * H, aggh, aggl,
        sum2, sq2, NN, H, KP2 / 32, KP2, KP1);
    finalize_kernel<<<1, 512, 0, stream>>>(sum2, sq2, gos + (size_t)i * H, bos + (size_t)i * H, H,
                                           1.f / NN, scale2, shift2);
    if (i < NL - 1) {
      bn2_kernel<false><<<(NN * (H / 2) + 255) / 256, 256, 0, stream>>>(aggh, aggl, scale2,
                                                                        shift2, hc, hout);
    } else {
      bn2_kernel<true><<<(NN * (H / 2) + 255) / 256, 256, 0, stream>>>(aggh, aggl, scale2,
                                                                       shift2, hc, hout);
    }
  }

  hipMemsetAsync(xpool, 0, (size_t)NG * H * 4, stream);
  bounds_kernel<<<1, 128, 0, stream>>>(batch, gstart);
  pool_kernel<<<dim3(NG, 8), 320, 0, stream>>>(hout, gstart, xpool);
}

// Round 7
// 1824.977 us; speedup vs baseline: 3.0706x; 1.2179x over previous
//
#include <hip/hip_runtime.h>
#include <hip/hip_fp16.h>
#include <stdint.h>

typedef _Float16 f16x8 __attribute__((ext_vector_type(8)));
typedef float f32x4 __attribute__((ext_vector_type(4)));

constexpr int NN  = 50000;   // nodes
constexpr int NE  = 800000;  // edges
constexpr int NG  = 64;      // graphs
constexpr int H   = 300;     // hidden
constexpr int H2  = 600;     // 2*hidden
constexpr int IND = 20;      // 2*PERIOD
constexpr int NL  = 5;

constexpr int MP  = 50048;   // rows padded to multiple of 128
constexpr int KP1 = 320;     // padded K stride for agg/u buffers (mult of 32)
constexpr int KP2 = 608;     // padded K stride for t buffers (mult of 32)
constexpr int NP1 = 640;     // padded N for gemm1 (5 x 128)
constexpr int NP2 = 384;     // padded N for gemm2 (3 x 128)
constexpr int HCS = 320;     // hc (fp16 h copy) row stride

// ---------------- fp16 helpers ----------------
static __device__ __forceinline__ ushort f2h(float f) {
  return __half_as_ushort(__float2half(f));
}
static __device__ __forceinline__ float h2f_lo(uint32_t u) {
  return __half2float(__ushort_as_half((ushort)(u & 0xFFFFu)));
}
static __device__ __forceinline__ float h2f_hi(uint32_t u) {
  return __half2float(__ushort_as_half((ushort)(u >> 16)));
}
static __device__ __forceinline__ uint32_t packh(float a, float b) {
  return (uint32_t)f2h(a) | ((uint32_t)f2h(b) << 16);
}

// ---------------- edge sort (counting sort by dst) ----------------

__global__ void hist_kernel(const int* __restrict__ dst, int* __restrict__ hist) {
  int i = blockIdx.x * blockDim.x + threadIdx.x;
  if (i < NE) atomicAdd(&hist[dst[i]], 1);
}

__global__ __launch_bounds__(1024) void scan_kernel(const int* __restrict__ hist,
                                                    int* __restrict__ offs,
                                                    int* __restrict__ cursor) {
  __shared__ int sdata[1024];
  __shared__ int srun;
  int tid = threadIdx.x;
  if (tid == 0) srun = 0;
  __syncthreads();
  for (int base = 0; base < NN; base += 1024) {
    int i = base + tid;
    int v = (i < NN) ? hist[i] : 0;
    sdata[tid] = v;
    __syncthreads();
    for (int ofs = 1; ofs < 1024; ofs <<= 1) {
      int t = (tid >= ofs) ? sdata[tid - ofs] : 0;
      __syncthreads();
      sdata[tid] += t;
      __syncthreads();
    }
    int run = srun;
    __syncthreads();
    if (i < NN) {
      int excl = run + sdata[tid] - v;
      offs[i] = excl;
      cursor[i] = excl;
    }
    if (tid == 0) srun = run + sdata[1023];
    __syncthreads();
  }
  if (tid == 0) offs[NN] = srun;
}

__global__ void scatter_kernel(const int* __restrict__ src, const int* __restrict__ dst,
                               const float* __restrict__ w, int* __restrict__ cursor,
                               int* __restrict__ ssrc, float* __restrict__ sw) {
  int i = blockIdx.x * blockDim.x + threadIdx.x;
  if (i < NE) {
    int d = dst[i];
    int p = atomicAdd(&cursor[d], 1);
    ssrc[p] = src[i];
    sw[p]   = w[i];
  }
}

// ---------------- pad zeroing (single fp16 buffer) ----------------

__global__ void padzero_kernel(ushort* __restrict__ b, int KPAD, int Ntrue) {
  long long nA = (long long)(MP - NN) * KPAD;
  int padc = KPAD - Ntrue;
  long long nB = (long long)NN * padc;
  long long total = nA + nB;
  long long stride = (long long)gridDim.x * blockDim.x;
  for (long long i = blockIdx.x * (long long)blockDim.x + threadIdx.x; i < total; i += stride) {
    long long off;
    if (i < nA) {
      off = (long long)NN * KPAD + i;
    } else {
      long long j = i - nA;
      long long r = j / padc;
      long long c = Ntrue + (j - r * padc);
      off = r * KPAD + c;
    }
    b[off] = 0;
  }
}

// ---------------- weight pre-pack (fp16): Bp[n][k] = fp16(W[k][n]) ----------------

__global__ void packW1_kernel(const float* __restrict__ W1s, ushort* __restrict__ Wp) {
  int idx = blockIdx.x * blockDim.x + threadIdx.x;
  if (idx >= NL * NP1 * KP1) return;
  int i = idx / (NP1 * KP1);
  int rem = idx - i * (NP1 * KP1);
  int n = rem / KP1;
  int k = rem - n * KP1;
  float v = (n < H2 && k < H) ? W1s[((long long)i * H + k) * H2 + n] : 0.f;
  Wp[idx] = f2h(v);
}

__global__ void packW2_kernel(const float* __restrict__ W2s, ushort* __restrict__ Wp) {
  int idx = blockIdx.x * blockDim.x + threadIdx.x;
  if (idx >= NL * NP2 * KP2) return;
  int i = idx / (NP2 * KP2);
  int rem = idx - i * (NP2 * KP2);
  int n = rem / KP2;
  int k = rem - n * KP2;
  float v = (n < H && k < H2) ? W2s[((long long)i * H2 + k) * H + n] : 0.f;
  Wp[idx] = f2h(v);
}

// ---------------- input linear: hc = fp16(x @ linW + linb), stride HCS ----------------

__global__ void lin_kernel(const float* __restrict__ x, const float* __restrict__ W,
                           const float* __restrict__ b, ushort* __restrict__ hc) {
  int idx = blockIdx.x * blockDim.x + threadIdx.x;
  if (idx >= NN * (H / 2)) return;
  int n = idx / (H / 2);
  int p = idx - n * (H / 2);
  int f = 2 * p;
  float a0 = b[f], a1 = b[f + 1];
  const float* xr = x + n * IND;
#pragma unroll
  for (int k = 0; k < IND; ++k) {
    float xv = xr[k];
    a0 = fmaf(xv, W[k * H + f], a0);
    a1 = fmaf(xv, W[k * H + f + 1], a1);
  }
  *reinterpret_cast<uint32_t*>(hc + (long long)n * HCS + f) = packh(a0, a1);
}

// ---------------- aggregation: fp16 hc gather, fp16 agg out ----------------

__global__ __launch_bounds__(192) void agg_kernel(const ushort* __restrict__ hc,
                                                  const int* __restrict__ offs,
                                                  const int* __restrict__ ssrc,
                                                  const float* __restrict__ sw,
                                                  ushort* __restrict__ agg) {
  int n = blockIdx.x;
  int t = threadIdx.x;
  if (t >= H / 2) return;
  int s = offs[n], e = offs[n + 1];
  float a0 = 0.f, a1 = 0.f;
  int i = s;
  for (; i + 3 < e; i += 4) {
    int sn0 = ssrc[i], sn1 = ssrc[i + 1], sn2 = ssrc[i + 2], sn3 = ssrc[i + 3];
    float w0 = sw[i], w1 = sw[i + 1], w2 = sw[i + 2], w3 = sw[i + 3];
    uint32_t u0 = *reinterpret_cast<const uint32_t*>(hc + (long long)sn0 * HCS + 2 * t);
    uint32_t u1 = *reinterpret_cast<const uint32_t*>(hc + (long long)sn1 * HCS + 2 * t);
    uint32_t u2 = *reinterpret_cast<const uint32_t*>(hc + (long long)sn2 * HCS + 2 * t);
    uint32_t u3 = *reinterpret_cast<const uint32_t*>(hc + (long long)sn3 * HCS + 2 * t);
    a0 = fmaf(w0, h2f_lo(u0), a0);
    a1 = fmaf(w0, h2f_hi(u0), a1);
    a0 = fmaf(w1, h2f_lo(u1), a0);
    a1 = fmaf(w1, h2f_hi(u1), a1);
    a0 = fmaf(w2, h2f_lo(u2), a0);
    a1 = fmaf(w2, h2f_hi(u2), a1);
    a0 = fmaf(w3, h2f_lo(u3), a0);
    a1 = fmaf(w3, h2f_hi(u3), a1);
  }
  for (; i < e; ++i) {
    int sn = ssrc[i];
    float w = sw[i];
    uint32_t u = *reinterpret_cast<const uint32_t*>(hc + (long long)sn * HCS + 2 * t);
    a0 = fmaf(w, h2f_lo(u), a0);
    a1 = fmaf(w, h2f_hi(u), a1);
  }
  *reinterpret_cast<uint32_t*>(agg + (long long)n * KP1 + 2 * t) = packh(a0, a1);
}

// ---------------- fp16 MFMA GEMM, LDS-staged A, fused column stats ----------------
// C = A @ Bp^T_packed + bias. A: [MP][KPAD] fp16. Bp: [Npad][KPAD] fp16 (Bp[n][k]=B[k][n]).
// A staged via global_load_lds (dbuf, BK=32, XOR-swizzled chunks); B reg-dbuf from L2.
// Grid: x = N-tile (fast) so same-A blocks dispatch together.

__global__ __launch_bounds__(256, 4) void gemm_mfma(
    const ushort* __restrict__ A, const ushort* __restrict__ Bp,
    const float* __restrict__ bias, ushort* __restrict__ C,
    float* __restrict__ sum, float* __restrict__ sq,
    int M, int Ntrue, int Ktiles, int KPAD, int Cstride) {
  __shared__ ushort AL[2][128 * 32];
  int tid = threadIdx.x;
  int lane = tid & 63, wid = tid >> 6;
  int wm = wid >> 1, wn = wid & 1;
  int lm = lane & 15, lg = lane >> 4;
  long long bm = (long long)blockIdx.y * 128;
  long long bn = (long long)blockIdx.x * 128;

  int srow = lane >> 2;   // 0..15: row within the wave's 16-row staging segment
  int slot = lane & 3;    // 16-byte chunk slot

  const ushort* Bb = Bp + (bn + wn * 64 + lm) * KPAD + lg * 8;

  f32x4 acc[4][4] = {};

  auto stageA = [&](int buf, int kt) {
    int k0 = kt * 32;
#pragma unroll
    for (int j = 0; j < 2; ++j) {
      int row = j * 64 + wid * 16 + srow;
      int cg = slot ^ ((row >> 1) & 3);   // swizzled source chunk
      long long go = (bm + row) * KPAD + k0 + cg * 8;
      ushort* l = &AL[buf][(j * 64 + wid * 16) * 32];  // wave-uniform base
      __builtin_amdgcn_global_load_lds(
          (const __attribute__((address_space(1))) void*)(A + go),
          (__attribute__((address_space(3))) void*)l, 16, 0, 0);
    }
  };

  f16x8 bcur[4], bnxt[4];
  stageA(0, 0);
#pragma unroll
  for (int i = 0; i < 4; ++i)
    bcur[i] = *reinterpret_cast<const f16x8*>(Bb + (long long)i * 16 * KPAD);
  __syncthreads();

  for (int kt = 0; kt < Ktiles; ++kt) {
    int cur = kt & 1;
    int nk = kt + 1;
    if (nk < Ktiles) {
      stageA(nk & 1, nk);
#pragma unroll
      for (int i = 0; i < 4; ++i)
        bnxt[i] = *reinterpret_cast<const f16x8*>(Bb + (long long)i * 16 * KPAD + nk * 32);
    }
    f16x8 a[4];
#pragma unroll
    for (int i = 0; i < 4; ++i) {
      int row = wm * 64 + i * 16 + lm;
      int c = lg ^ ((row >> 1) & 3);
      a[i] = *reinterpret_cast<const f16x8*>(&AL[cur][row * 32 + c * 8]);
    }
#pragma unroll
    for (int mf = 0; mf < 4; ++mf)
#pragma unroll
      for (int nf = 0; nf < 4; ++nf)
        acc[mf][nf] = __builtin_amdgcn_mfma_f32_16x16x32_f16(a[mf], bcur[nf], acc[mf][nf], 0, 0, 0);
    __syncthreads();
#pragma unroll
    for (int i = 0; i < 4; ++i) bcur[i] = bnxt[i];
  }

  int colb = (int)bn + wn * 64 + lm;
#pragma unroll
  for (int nf = 0; nf < 4; ++nf) {
    int col = colb + nf * 16;
    bool cok = col < Ntrue;
    float bv = cok ? bias[col] : 0.f;
    float cs = 0.f, cq = 0.f;
#pragma unroll
    for (int mf = 0; mf < 4; ++mf) {
      int row = (int)bm + wm * 64 + mf * 16 + lg * 4;
      f32x4 v = acc[mf][nf];
#pragma unroll
      for (int e = 0; e < 4; ++e) {
        if (cok && row + e < M) {
          float w = v[e] + bv;
          cs += w;
          cq = fmaf(w, w, cq);
          C[(long long)(row + e) * Cstride + col] = f2h(w);
        }
      }
    }
    cs += __shfl_xor(cs, 16);
    cq += __shfl_xor(cq, 16);
    cs += __shfl_xor(cs, 32);
    cq += __shfl_xor(cq, 32);
    if (lg == 0 && cok) {
      atomicAdd(&sum[col], cs);
      atomicAdd(&sq[col], cq);
    }
  }
}

// ---------------- BN finalize ----------------

__global__ void finalize_kernel(const float* __restrict__ sum, const float* __restrict__ sq,
                                const float* __restrict__ g, const float* __restrict__ be,
                                int C, float invM, float* __restrict__ scale,
                                float* __restrict__ shift) {
  int c = blockIdx.x * blockDim.x + threadIdx.x;
  if (c < C) {
    float m = sum[c] * invM;
    float v = sq[c] * invM - m * m;
    float sc = g[c] * rsqrtf(v + 1e-5f);
    scale[c] = sc;
    shift[c] = be[c] - m * sc;
  }
}

// ---------------- BN apply ----------------

__global__ void bn1_kernel(ushort* __restrict__ t_, const float* __restrict__ scale,
                           const float* __restrict__ shift) {
  int idx = blockIdx.x * blockDim.x + threadIdx.x;
  if (idx >= NN * (H2 / 2)) return;
  int r = idx / (H2 / 2);
  int p = idx - r * (H2 / 2);
  int c = 2 * p;
  uint32_t* tp = reinterpret_cast<uint32_t*>(t_ + (long long)r * KP2 + c);
  uint32_t u = *tp;
  float w0 = fmaxf(fmaf(h2f_lo(u), scale[c], shift[c]), 0.f);
  float w1 = fmaxf(fmaf(h2f_hi(u), scale[c + 1], shift[c + 1]), 0.f);
  *tp = packh(w0, w1);
}

// bn2: fp16 u (stride KP1) -> fp16 hc (intermediate) or f32 hout (last)
template <bool LAST>
__global__ void bn2_kernel(const ushort* __restrict__ u_, const float* __restrict__ scale,
                           const float* __restrict__ shift, ushort* __restrict__ hc,
                           float* __restrict__ out) {
  int idx = blockIdx.x * blockDim.x + threadIdx.x;
  if (idx >= NN * (H / 2)) return;
  int r = idx / (H / 2);
  int p = idx - r * (H / 2);
  int c = 2 * p;
  uint32_t u = *reinterpret_cast<const uint32_t*>(u_ + (long long)r * KP1 + c);
  float w0 = fmaf(h2f_lo(u), scale[c], shift[c]);
  float w1 = fmaf(h2f_hi(u), scale[c + 1], shift[c + 1]);
  if (LAST) {
    *reinterpret_cast<float2*>(out + (long long)r * H + c) = make_float2(w0, w1);
  } else {
    w0 = fmaxf(w0, 0.f);
    w1 = fmaxf(w1, 0.f);
    *reinterpret_cast<uint32_t*>(hc + (long long)r * HCS + c) = packh(w0, w1);
  }
}

// ---------------- graph pooling ----------------

__global__ void bounds_kernel(const int* __restrict__ batch, int* __restrict__ gstart) {
  int g = threadIdx.x;
  if (g > NG) return;
  if (g == NG) { gstart[NG] = NN; return; }
  int lo = 0, hi = NN;
  while (lo < hi) {
    int mid = (lo + hi) >> 1;
    if (batch[mid] < g) lo = mid + 1; else hi = mid;
  }
  gstart[g] = lo;
}

__global__ __launch_bounds__(320) void pool_kernel(const float* __restrict__ h,
                                                   const int* __restrict__ gstart,
                                                   float* __restrict__ xpool) {
  int g = blockIdx.x;
  int f = threadIdx.x;
  if (f >= H) return;
  int s = gstart[g], e = gstart[g + 1];
  float acc = 0.f;
  for (int r = s + blockIdx.y; r < e; r += gridDim.y) acc += h[(long long)r * H + f];
  atomicAdd(&xpool[g * H + f], acc);
}

// ---------------- driver ----------------

extern "C" void kernel_launch(void* const* d_in, const int* in_sizes, int n_in,
                              void* d_out, int out_size, void* d_ws, size_t ws_size,
                              hipStream_t stream) {
  const int*   batch = (const int*)d_in[0];
  const float* x     = (const float*)d_in[1];
  const int*   eidx  = (const int*)d_in[2];
  const float* eattr = (const float*)d_in[3];
  const float* linW  = (const float*)d_in[4];
  const float* linb  = (const float*)d_in[5];
  const float* W1s   = (const float*)d_in[6];
  const float* b1s   = (const float*)d_in[7];
  const float* g1s   = (const float*)d_in[8];
  const float* be1s  = (const float*)d_in[9];
  const float* W2s   = (const float*)d_in[10];
  const float* b2s   = (const float*)d_in[11];
  const float* gos   = (const float*)d_in[12];
  const float* bos   = (const float*)d_in[13];

  const int* esrc = eidx;
  const int* edst = eidx + NE;

  char* p = (char*)d_ws;
  auto alloc = [&](size_t bytes) {
    char* r = p;
    p += (bytes + 255) & ~(size_t)255;
    return r;
  };
  ushort* tb   = (ushort*)alloc((size_t)MP * KP2 * 2);   // t (fp16)
  ushort* ub   = (ushort*)alloc((size_t)MP * KP1 * 2);   // agg, reused as u (fp16)
  ushort* hc   = (ushort*)alloc((size_t)NN * HCS * 2);   // fp16 h copy
  ushort* W1p  = (ushort*)alloc((size_t)NL * NP1 * KP1 * 2);
  ushort* W2p  = (ushort*)alloc((size_t)NL * NP2 * KP2 * 2);
  int*    hist   = (int*)alloc((size_t)NN * 4);
  int*    offs   = (int*)alloc((size_t)(NN + 64) * 4);
  int*    cursor = (int*)alloc((size_t)NN * 4);
  int*    ssrc   = (int*)alloc((size_t)NE * 4);
  float*  sw     = (float*)alloc((size_t)NE * 4);
  float*  sum1   = (float*)alloc((size_t)(H2 * 2 + H * 2) * 4);
  float*  sq1    = sum1 + H2;
  float*  sum2   = sq1 + H2;
  float*  sq2    = sum2 + H;
  float*  scale1 = (float*)alloc((size_t)(H2 * 2 + H * 2) * 4);
  float*  shift1 = scale1 + H2;
  float*  scale2 = shift1 + H2;
  float*  shift2 = scale2 + H;
  int*    gstart = (int*)alloc((size_t)(NG + 1) * 4);
  size_t needed = (size_t)(p - (char*)d_ws);
  if (ws_size < needed) return;

  float* hout  = (float*)d_out;
  float* xpool = hout + (long long)NN * H;

  padzero_kernel<<<1024, 256, 0, stream>>>(tb, KP2, H2);
  padzero_kernel<<<1024, 256, 0, stream>>>(ub, KP1, H);

  packW1_kernel<<<(NL * NP1 * KP1 + 255) / 256, 256, 0, stream>>>(W1s, W1p);
  packW2_kernel<<<(NL * NP2 * KP2 + 255) / 256, 256, 0, stream>>>(W2s, W2p);

  hipMemsetAsync(hist, 0, (size_t)NN * 4, stream);
  hist_kernel<<<(NE + 255) / 256, 256, 0, stream>>>(edst, hist);
  scan_kernel<<<1, 1024, 0, stream>>>(hist, offs, cursor);
  scatter_kernel<<<(NE + 255) / 256, 256, 0, stream>>>(esrc, edst, eattr, cursor, ssrc, sw);

  lin_kernel<<<(NN * (H / 2) + 255) / 256, 256, 0, stream>>>(x, linW, linb, hc);

  for (int i = 0; i < NL; ++i) {
    agg_kernel<<<NN, 192, 0, stream>>>(hc, offs, ssrc, sw, ub);
    hipMemsetAsync(sum1, 0, (size_t)(H2 * 2 + H * 2) * 4, stream);

    // t = agg @ W1 + b1  (fp16 out, stats fused); grid x = N-tiles
    gemm_mfma<<<dim3(NP1 / 128, MP / 128), 256, 0, stream>>>(
        ub, W1p + (size_t)i * NP1 * KP1, b1s + (size_t)i * H2, tb,
        sum1, sq1, NN, H2, KP1 / 32, KP1, KP2);
    finalize_kernel<<<(H2 + 255) / 256, 256, 0, stream>>>(sum1, sq1, g1s + (size_t)i * H2,
                                                          be1s + (size_t)i * H2, H2, 1.f / NN,
                                                          scale1, shift1);
    bn1_kernel<<<(NN * (H2 / 2) + 255) / 256, 256, 0, stream>>>(tb, scale1, shift1);

    // u = t' @ W2 + b2 (fp16 into ub, stats fused)
    gemm_mfma<<<dim3(NP2 / 128, MP / 128), 256, 0, stream>>>(
        tb, W2p + (size_t)i * NP2 * KP2, b2s + (size_t)i * H, ub,
        sum2, sq2, NN, H, KP2 / 32, KP2, KP1);
    finalize_kernel<<<1, 512, 0, stream>>>(sum2, sq2, gos + (size_t)i * H, bos + (size_t)i * H, H,
                                           1.f / NN, scale2, shift2);
    if (i < NL - 1) {
      bn2_kernel<false><<<(NN * (H / 2) + 255) / 256, 256, 0, stream>>>(ub, scale2, shift2,
                                                                        hc, hout);
    } else {
      bn2_kernel<true><<<(NN * (H / 2) + 255) / 256, 256, 0, stream>>>(ub, scale2, shift2,
                                                                       hc, hout);
    }
  }

  hipMemsetAsync(xpool, 0, (size_t)NG * H * 4, stream);
  bounds_kernel<<<1, 128, 0, stream>>>(batch, gstart);
  pool_kernel<<<dim3(NG, 8), 320, 0, stream>>>(hout, gstart, xpool);
}